// Round 12
// baseline (320.293 us; speedup 1.0000x reference)
//
#include <hip/hip_runtime.h>
#include <math.h>

#define N_NODES 50000
#define N_EDGES 800000
#define BN_EPS_F 1e-5f
#define SCAN_BS 512
#define SCAN_NB 98   // ceil(50000/512)
#define RC 391       // row-chunks of 128 rows
#define RQ 49        // ceil(RC/8)
#define GXP 392      // padded partials stride (>= RC)
#define FILL_CH 4096 // edges per fill block

typedef unsigned short ushort_t;
typedef unsigned int uint_t;
typedef __attribute__((ext_vector_type(8))) short bf16x8;
typedef __attribute__((ext_vector_type(4))) float f32x4;

static __device__ __forceinline__ float4 ld4(const float* p) {
    return *reinterpret_cast<const float4*>(p);
}
static __device__ __forceinline__ float bf2f(ushort_t u) {
    return __uint_as_float(((uint_t)u) << 16);
}
static __device__ __forceinline__ ushort_t f2b(float f) {
    uint_t u = __float_as_uint(f);
    u += 0x7fffu + ((u >> 16) & 1u);
    return (ushort_t)(u >> 16);
}

// ---------------- CSR build ----------------

__global__ void k_zero_i32(int* __restrict__ p, int n) {
    int i = blockIdx.x * blockDim.x + threadIdx.x;
    if (i < n) p[i] = 0;
}

// fused: countrank (even blocks; deg2 padded 1 counter/64B line) + x->bf16 (odd) + W transposes (tail)
__global__ void k_pre(const int* __restrict__ dst, int* __restrict__ deg2,
                      ushort_t* __restrict__ rank,
                      const float* __restrict__ x, ushort_t* __restrict__ xb,
                      const float* __restrict__ W1l, const float* __restrict__ W1r,
                      const float* __restrict__ W2l, ushort_t* __restrict__ wt1l,
                      ushort_t* __restrict__ wt1r, ushort_t* __restrict__ wt2l) {
    int b = blockIdx.x;
    if (b < 6250) {
        int role = b & 1;
        int id = (b >> 1) * 256 + threadIdx.x;   // < 800000 exact
        if (role == 0) {
            rank[id] = (ushort_t)atomicAdd(&deg2[dst[id] * 16], 1);
        } else {
            float4 a = ld4(x + (size_t)id * 8);
            float4 c = ld4(x + (size_t)id * 8 + 4);
            uint_t o0 = (uint_t)f2b(a.x) | ((uint_t)f2b(a.y) << 16);
            uint_t o1 = (uint_t)f2b(a.z) | ((uint_t)f2b(a.w) << 16);
            uint_t o2 = (uint_t)f2b(c.x) | ((uint_t)f2b(c.y) << 16);
            uint_t o3 = (uint_t)f2b(c.z) | ((uint_t)f2b(c.w) << 16);
            *reinterpret_cast<uint4*>(xb + (size_t)id * 8) = make_uint4(o0, o1, o2, o3);
        }
    } else {
        int idx = (b - 6250) * 256 + threadIdx.x;   // 0..65535
        if (idx < 16384) {
            int f = idx >> 7, k = idx & 127;
            wt1l[idx] = f2b(W1l[(size_t)k * 128 + f]);
        } else if (idx < 32768) {
            int j = idx - 16384;
            int f = j >> 7, k = j & 127;
            wt1r[j] = f2b(W1r[(size_t)k * 128 + f]);
        } else {
            int j = idx - 32768;                    // F=256 K=128
            int f = j >> 7, k = j & 127;
            wt2l[j] = f2b(W2l[(size_t)k * 256 + f]);
        }
    }
}

__global__ void k_scan1(const int* __restrict__ deg2, int* __restrict__ offs, int* __restrict__ bsum) {
    __shared__ int sh[SCAN_BS];
    int t = threadIdx.x;
    int g = blockIdx.x * SCAN_BS + t;
    int v = (g < N_NODES) ? deg2[g * 16] : 0;
    sh[t] = v;
    __syncthreads();
    for (int off = 1; off < SCAN_BS; off <<= 1) {
        int add = (t >= off) ? sh[t - off] : 0;
        __syncthreads();
        sh[t] += add;
        __syncthreads();
    }
    if (g < N_NODES) offs[g] = sh[t] - v;
    if (t == SCAN_BS - 1) bsum[blockIdx.x] = sh[t];
}

__global__ void k_scan2(int* __restrict__ bsum, int nb) {
    __shared__ int sh[128];
    int t = threadIdx.x;
    int v = (t < nb) ? bsum[t] : 0;
    sh[t] = v;
    __syncthreads();
    for (int off = 1; off < 128; off <<= 1) {
        int add = (t >= off) ? sh[t - off] : 0;
        __syncthreads();
        sh[t] += add;
        __syncthreads();
    }
    if (t < nb) bsum[t] = sh[t] - v;
}

__global__ void k_scan3(const int* __restrict__ deg2, int* __restrict__ offs,
                        const int* __restrict__ bsum, float* __restrict__ inv_deg,
                        int* __restrict__ degc) {
    int g = blockIdx.x * blockDim.x + threadIdx.x;
    if (g < N_NODES) {
        offs[g] += bsum[g / SCAN_BS];
        int d = deg2[g * 16];
        degc[g] = d;
        inv_deg[g] = 1.0f / (float)(d > 1 ? d : 1);
    }
}

// XCD-partitioned scatter: class (bid&7) writes only its contiguous 1/8 of eids
// -> full-line writebacks from a single L2. dst re-reads are L3-resident.
__global__ __launch_bounds__(256) void k_fill3(
        const int* __restrict__ src, const int* __restrict__ dst,
        const int* __restrict__ offs, const ushort_t* __restrict__ rank,
        ushort_t* __restrict__ eids) {
    const int cls = blockIdx.x & 7;
    const int chunk = blockIdx.x >> 3;
    const int lo = cls * (N_NODES / 8);
    const int hi = lo + (N_NODES / 8);
    int base = chunk * FILL_CH + threadIdx.x;
#pragma unroll
    for (int it = 0; it < FILL_CH / 256; ++it) {
        int e = base + it * 256;
        if (e < N_EDGES) {
            int d = dst[e];
            if (d >= lo && d < hi)
                eids[offs[d] + (int)rank[e]] = (ushort_t)src[e];
        }
    }
}

// ---------------- late weight prep with FUSED BN reduce ----------------
// each block redundantly reduces partials[2F][GXP] (g-contiguous, float4) -> sc/sh in LDS

__global__ __launch_bounds__(256) void k_prep2(
        const float* __restrict__ W2r, const float* __restrict__ b2,
        const float* __restrict__ g1, const float* __restrict__ be1,
        const float* __restrict__ parts, ushort_t* __restrict__ wt2r,
        float* __restrict__ bias2, float* __restrict__ scsh1g) {
    __shared__ float sc[128], sh[128];
    const int t = threadIdx.x;
    if (t < 128) {
        float s = 0.f, q2 = 0.f;
        const float* ps = parts + (size_t)t * GXP;
        const float* pq = parts + (size_t)(128 + t) * GXP;
        for (int g = 0; g + 4 <= RC; g += 4) {
            float4 a = ld4(ps + g), b = ld4(pq + g);
            s += a.x + a.y + a.z + a.w;
            q2 += b.x + b.y + b.z + b.w;
        }
        for (int g = RC & ~3; g < RC; ++g) { s += ps[g]; q2 += pq[g]; }
        float mean = s * (1.0f / N_NODES);
        float var = q2 * (1.0f / N_NODES) - mean * mean;
        float scv = g1[t] * rsqrtf(var + BN_EPS_F);
        sc[t] = scv;
        sh[t] = be1[t] - mean * scv;
    }
    __syncthreads();
    const int bid = blockIdx.x;
    if (bid < 128) {
        int idx = bid * 256 + t;                // F=256 K=128
        int f = idx >> 7, k = idx & 127;
        wt2r[idx] = f2b(sc[k] * W2r[(size_t)k * 256 + f]);
    } else {
        float s = b2[t];
        for (int k = 0; k < 128; ++k) s += sh[k] * W2r[(size_t)k * 256 + t];
        bias2[t] = s;
        if (t < 128) { scsh1g[t] = sc[t]; scsh1g[128 + t] = sh[t]; }
    }
}

__global__ __launch_bounds__(256) void k_prep3(
        const float* __restrict__ W3l, const float* __restrict__ W3r,
        const float* __restrict__ b3, const float* __restrict__ g2,
        const float* __restrict__ be2, const float* __restrict__ parts,
        ushort_t* __restrict__ wt3l, ushort_t* __restrict__ wt3r,
        float* __restrict__ bias3l, float* __restrict__ bias3r) {
    __shared__ float sc[256], sh[256];
    const int t = threadIdx.x;
    {
        float s = 0.f, q2 = 0.f;
        const float* ps = parts + (size_t)t * GXP;
        const float* pq = parts + (size_t)(256 + t) * GXP;
        for (int g = 0; g + 4 <= RC; g += 4) {
            float4 a = ld4(ps + g), b = ld4(pq + g);
            s += a.x + a.y + a.z + a.w;
            q2 += b.x + b.y + b.z + b.w;
        }
        for (int g = RC & ~3; g < RC; ++g) { s += ps[g]; q2 += pq[g]; }
        float mean = s * (1.0f / N_NODES);
        float var = q2 * (1.0f / N_NODES) - mean * mean;
        float scv = g2[t] * rsqrtf(var + BN_EPS_F);
        sc[t] = scv;
        sh[t] = be2[t] - mean * scv;
    }
    __syncthreads();
    const int bid = blockIdx.x;
    if (bid < 256) {
        int half = bid >> 7;
        int idx = (bid & 127) * 256 + t;        // F=128 K=256
        int f = idx >> 8, k = idx & 255;
        const float* W = half ? W3r : W3l;
        ushort_t* WT = half ? wt3r : wt3l;
        WT[idx] = f2b(sc[k] * W[(size_t)k * 128 + f]);
    } else {
        int f = t & 127;
        const float* W = (t < 128) ? W3l : W3r;
        float s = (t < 128) ? 0.f : b3[f];
        for (int k = 0; k < 256; ++k) s += sh[k] * W[(size_t)k * 128 + f];
        ((t < 128) ? bias3l : bias3r)[f] = s;
    }
}

// ---------------- gather core: one 16-lane GROUP per node, 8-deep pipeline ----------------

#define ACCUM8(a) do { \
    acc[0] += bf2f((ushort_t)(a).x); acc[1] += bf2f((ushort_t)((a).x >> 16)); \
    acc[2] += bf2f((ushort_t)(a).y); acc[3] += bf2f((ushort_t)((a).y >> 16)); \
    acc[4] += bf2f((ushort_t)(a).z); acc[5] += bf2f((ushort_t)((a).z >> 16)); \
    acc[6] += bf2f((ushort_t)(a).w); acc[7] += bf2f((ushort_t)((a).w >> 16)); } while (0)

static __device__ __forceinline__ void gather_rows_g(
        const ushort_t* __restrict__ h, const ushort_t* __restrict__ eids,
        int beg, int d, size_t coff, float* acc) {
    int j = 0;
    for (; j + 8 <= d; j += 8) {
        uint4 a[8];
#pragma unroll
        for (int k = 0; k < 8; ++k) {
            int s = eids[beg + j + k];
            a[k] = *reinterpret_cast<const uint4*>(h + (size_t)s * 128 + coff);
        }
#pragma unroll
        for (int k = 0; k < 8; ++k) ACCUM8(a[k]);
    }
    for (; j + 4 <= d; j += 4) {
        uint4 a[4];
#pragma unroll
        for (int k = 0; k < 4; ++k) {
            int s = eids[beg + j + k];
            a[k] = *reinterpret_cast<const uint4*>(h + (size_t)s * 128 + coff);
        }
#pragma unroll
        for (int k = 0; k < 4; ++k) ACCUM8(a[k]);
    }
    for (; j + 2 <= d; j += 2) {
        int s0 = eids[beg + j];
        int s1 = eids[beg + j + 1];
        uint4 a = *reinterpret_cast<const uint4*>(h + (size_t)s0 * 128 + coff);
        uint4 b = *reinterpret_cast<const uint4*>(h + (size_t)s1 * 128 + coff);
        ACCUM8(a); ACCUM8(b);
    }
    if (j < d) {
        int s0 = eids[beg + j];
        uint4 a = *reinterpret_cast<const uint4*>(h + (size_t)s0 * 128 + coff);
        ACCUM8(a);
    }
}

template<int BN>
__global__ __launch_bounds__(256) void k_agg16(
        const ushort_t* __restrict__ h, const ushort_t* __restrict__ eids,
        const int* __restrict__ offs, const int* __restrict__ deg,
        const float* __restrict__ inv_deg, const float* __restrict__ scsh,
        ushort_t* __restrict__ out) {
    const int node = blockIdx.x * 16 + (threadIdx.x >> 4);
    const int lr = threadIdx.x & 15;
    if (node >= N_NODES) return;
    float acc[8];
#pragma unroll
    for (int v = 0; v < 8; ++v) acc[v] = 0.f;
    const int beg = offs[node];
    const int d = deg[node];
    const size_t coff = (size_t)lr * 8;
    gather_rows_g(h, eids, beg, d, coff, acc);

    float sc = inv_deg[node];
    if (BN) {
        float4 sa0 = ld4(&scsh[lr * 8]), sa1 = ld4(&scsh[lr * 8 + 4]);
        float4 sb0 = ld4(&scsh[128 + lr * 8]), sb1 = ld4(&scsh[128 + lr * 8 + 4]);
        if (d > 0) {
            acc[0] = acc[0] * sc * sa0.x + sb0.x; acc[1] = acc[1] * sc * sa0.y + sb0.y;
            acc[2] = acc[2] * sc * sa0.z + sb0.z; acc[3] = acc[3] * sc * sa0.w + sb0.w;
            acc[4] = acc[4] * sc * sa1.x + sb1.x; acc[5] = acc[5] * sc * sa1.y + sb1.y;
            acc[6] = acc[6] * sc * sa1.z + sb1.z; acc[7] = acc[7] * sc * sa1.w + sb1.w;
        } else {
#pragma unroll
            for (int v = 0; v < 8; ++v) acc[v] = 0.f;
        }
    } else {
#pragma unroll
        for (int v = 0; v < 8; ++v) acc[v] *= sc;
    }
    uint4 o;
    o.x = (uint_t)f2b(acc[0]) | ((uint_t)f2b(acc[1]) << 16);
    o.y = (uint_t)f2b(acc[2]) | ((uint_t)f2b(acc[3]) << 16);
    o.z = (uint_t)f2b(acc[4]) | ((uint_t)f2b(acc[5]) << 16);
    o.w = (uint_t)f2b(acc[6]) | ((uint_t)f2b(acc[7]) << 16);
    *reinterpret_cast<uint4*>(out + (size_t)node * 128 + coff) = o;
}

__global__ __launch_bounds__(256) void k_agg_reparam(
        const ushort_t* __restrict__ t3, const ushort_t* __restrict__ eids,
        const int* __restrict__ offs, const int* __restrict__ deg,
        const float* __restrict__ inv_deg, const ushort_t* __restrict__ u,
        const float* __restrict__ eps, float* __restrict__ z) {
    const int node = blockIdx.x * 16 + (threadIdx.x >> 4);
    const int lr = threadIdx.x & 15;
    if (node >= N_NODES) return;
    float acc[8];
#pragma unroll
    for (int v = 0; v < 8; ++v) acc[v] = 0.f;
    const int beg = offs[node];
    const int d = deg[node];
    const size_t coff = (size_t)lr * 8;
    gather_rows_g(t3, eids, beg, d, coff, acc);
    float ls[8];
#pragma unroll
    for (int v = 0; v < 8; ++v) ls[v] = __shfl_down(acc[v], 8);

    if (lr < 8) {
        float sc = inv_deg[node];
        uint4 um4 = *reinterpret_cast<const uint4*>(u + (size_t)node * 128 + lr * 8);
        uint4 ul4 = *reinterpret_cast<const uint4*>(u + (size_t)node * 128 + 64 + lr * 8);
        const float* ep = eps + (size_t)node * 64 + lr * 8;
        float4 e0 = ld4(ep), e1 = ld4(ep + 4);
        float um[8], ul[8];
        um[0] = bf2f((ushort_t)um4.x); um[1] = bf2f((ushort_t)(um4.x >> 16));
        um[2] = bf2f((ushort_t)um4.y); um[3] = bf2f((ushort_t)(um4.y >> 16));
        um[4] = bf2f((ushort_t)um4.z); um[5] = bf2f((ushort_t)(um4.z >> 16));
        um[6] = bf2f((ushort_t)um4.w); um[7] = bf2f((ushort_t)(um4.w >> 16));
        ul[0] = bf2f((ushort_t)ul4.x); ul[1] = bf2f((ushort_t)(ul4.x >> 16));
        ul[2] = bf2f((ushort_t)ul4.y); ul[3] = bf2f((ushort_t)(ul4.y >> 16));
        ul[4] = bf2f((ushort_t)ul4.z); ul[5] = bf2f((ushort_t)(ul4.z >> 16));
        ul[6] = bf2f((ushort_t)ul4.w); ul[7] = bf2f((ushort_t)(ul4.w >> 16));
        float4 o0, o1;
        o0.x = (acc[0] * sc + um[0]) + expf(ls[0] * sc + ul[0]) * e0.x;
        o0.y = (acc[1] * sc + um[1]) + expf(ls[1] * sc + ul[1]) * e0.y;
        o0.z = (acc[2] * sc + um[2]) + expf(ls[2] * sc + ul[2]) * e0.z;
        o0.w = (acc[3] * sc + um[3]) + expf(ls[3] * sc + ul[3]) * e0.w;
        o1.x = (acc[4] * sc + um[4]) + expf(ls[4] * sc + ul[4]) * e1.x;
        o1.y = (acc[5] * sc + um[5]) + expf(ls[5] * sc + ul[5]) * e1.y;
        o1.z = (acc[6] * sc + um[6]) + expf(ls[6] * sc + ul[6]) * e1.z;
        o1.w = (acc[7] * sc + um[7]) + expf(ls[7] * sc + ul[7]) * e1.w;
        float* zp = z + (size_t)node * 64 + lr * 8;
        *reinterpret_cast<float4*>(zp) = o0;
        *reinterpret_cast<float4*>(zp + 4) = o1;
    }
}

// ---------------- direct-fragment MFMA GEMM, high occupancy ----------------
// Block: 4 waves as 2x2 -> 128 rows x 64 cols; wave tile 64x32 (acc 4x2).
// 64-K register prefetch per stall-round (8 av + 4 bv loads), ~110 VGPR ->
// launch_bounds(256,4) = 16 waves/CU. XCD-class decode keeps all col/out
// variants of a row-chunk on one L2 (full-line writebacks, A-panel reuse).

template<int RELU, int DUAL, int STATS, int SEL3, int K, int YT>
__global__ __launch_bounds__(256, 4) void k_gemm_direct(
        const ushort_t* __restrict__ A1, const ushort_t* __restrict__ A2,
        const ushort_t* __restrict__ B1, const ushort_t* __restrict__ B2,
        const float* __restrict__ bias, ushort_t* __restrict__ out,
        int F, float* __restrict__ partials,
        const float* __restrict__ bias2, ushort_t* __restrict__ out2) {
    const int bid = blockIdx.x;
    const int grp = bid >> 3;
    const int y = grp / RQ;
    const int rq = grp - y * RQ;
    const int r = (bid & 7) + (rq << 3);
    if (r >= RC) return;
    const int row0 = r * 128;

    int colblk = y, outsel = 0;
    if (SEL3) { colblk = y & 1; outsel = y >> 1; }
    const int col0 = colblk * 64;
    const ushort_t* __restrict__ Bp = (SEL3 && outsel) ? B2 : B1;
    const float* __restrict__ biasp = (SEL3 && outsel) ? bias2 : bias;
    ushort_t* __restrict__ outp = (SEL3 && outsel) ? out2 : out;

    const int tid = threadIdx.x;
    const int lane = tid & 63;
    const int w = tid >> 6;
    const int q = lane >> 4, lr = lane & 15;
    const int wrow = row0 + (w >> 1) * 64;      // wave's 64-row strip
    const int wcol = col0 + (w & 1) * 32;       // wave's 32-col strip

    int arow[4];
#pragma unroll
    for (int mf = 0; mf < 4; ++mf) {
        int rr = wrow + mf * 16 + lr;
        arow[mf] = rr < N_NODES ? rr : N_NODES - 1;
    }

    f32x4 acc[4][2];
#pragma unroll
    for (int mf = 0; mf < 4; ++mf)
#pragma unroll
        for (int nf = 0; nf < 2; ++nf)
            acc[mf][nf] = (f32x4){0.f, 0.f, 0.f, 0.f};

#pragma unroll
    for (int m = 0; m < (DUAL ? 2 : 1); ++m) {
        const ushort_t* __restrict__ A = m ? A2 : A1;
        const ushort_t* __restrict__ B = m ? B2 : Bp;
#pragma unroll
        for (int kh = 0; kh < K / 64; ++kh) {
            const int kb = kh * 64;
            bf16x8 av[2][4], bv[2][2];          // [k0][frag]
#pragma unroll
            for (int k0 = 0; k0 < 2; ++k0) {
#pragma unroll
                for (int f = 0; f < 4; ++f)
                    av[k0][f] = *reinterpret_cast<const bf16x8*>(
                        A + (size_t)arow[f] * K + kb + k0 * 32 + q * 8);
#pragma unroll
                for (int f = 0; f < 2; ++f)
                    bv[k0][f] = *reinterpret_cast<const bf16x8*>(
                        B + (size_t)(wcol + f * 16 + lr) * K + kb + k0 * 32 + q * 8);
            }
#pragma unroll
            for (int k0 = 0; k0 < 2; ++k0)
#pragma unroll
                for (int mf = 0; mf < 4; ++mf)
#pragma unroll
                    for (int nf = 0; nf < 2; ++nf)
                        acc[mf][nf] = __builtin_amdgcn_mfma_f32_16x16x32_bf16(
                            av[k0][mf], bv[k0][nf], acc[mf][nf], 0, 0, 0);
        }
    }

    // ---- epilogue: bias/relu/stats in regs, LDS transpose, coalesced 16B stores
    __shared__ __align__(16) short lw[4][64][36];     // 18432 B
    __shared__ float sdf[2][8][64];                   // 4096 B

    float s[2], s2[2];
#pragma unroll
    for (int nf = 0; nf < 2; ++nf) { s[nf] = 0.f; s2[nf] = 0.f; }
#pragma unroll
    for (int nf = 0; nf < 2; ++nf) {
        float bvs = biasp[wcol + nf * 16 + lr];
#pragma unroll
        for (int mf = 0; mf < 4; ++mf) {
#pragma unroll
            for (int b = 0; b < 4; ++b) {
                int rloc = mf * 16 + q * 4 + b;       // row within wave strip
                float v = acc[mf][nf][b] + bvs;
                if (RELU) v = fmaxf(v, 0.f);
                if (STATS && (wrow + rloc) < N_NODES) { s[nf] += v; s2[nf] += v * v; }
                lw[w][rloc][nf * 16 + lr] = (short)f2b(v);
            }
        }
    }
    // same-wave LDS readback (compiler inserts lgkmcnt wait)
#pragma unroll
    for (int it = 0; it < 4; ++it) {
        int row = it * 16 + (lane >> 2);
        int gr = wrow + row;
        if (gr < N_NODES) {
            uint4 vv = *reinterpret_cast<const uint4*>(&lw[w][row][(lane & 3) * 8]);
            *reinterpret_cast<uint4*>(outp + (size_t)gr * F + wcol + (lane & 3) * 8) = vv;
        }
    }

    if constexpr (STATS) {
        const int u = (w >> 1) * 4 + q;               // 8 contributors per col
#pragma unroll
        for (int nf = 0; nf < 2; ++nf) {
            int cb = (w & 1) * 32 + nf * 16 + lr;     // 0..63 within block
            sdf[0][u][cb] = s[nf];
            sdf[1][u][cb] = s2[nf];
        }
        __syncthreads();
        if (tid < 64) {
            float ss = 0.f, qq = 0.f;
#pragma unroll
            for (int u2 = 0; u2 < 8; ++u2) {
                ss += sdf[0][u2][tid];
                qq += sdf[1][u2][tid];
            }
            int cg = col0 + tid;
            partials[(size_t)cg * GXP + r] = ss;
            partials[(size_t)(F + cg) * GXP + r] = qq;
        }
    }
}

// ---------------- launch ----------------

extern "C" void kernel_launch(void* const* d_in, const int* in_sizes, int n_in,
                              void* d_out, int out_size, void* d_ws, size_t ws_size,
                              hipStream_t stream) {
    (void)in_sizes; (void)n_in; (void)out_size; (void)ws_size;
    const float* x   = (const float*)d_in[0];
    const int*   src = (const int*)d_in[1];
    const int*   dst = (const int*)d_in[2];
    const float* eps = (const float*)d_in[3];
    const float* W1l = (const float*)d_in[4];
    const float* W1r = (const float*)d_in[5];
    const float* b1  = (const float*)d_in[6];
    const float* g1  = (const float*)d_in[7];
    const float* be1 = (const float*)d_in[8];
    const float* W2l = (const float*)d_in[9];
    const float* W2r = (const float*)d_in[10];
    const float* b2  = (const float*)d_in[11];
    const float* g2  = (const float*)d_in[12];
    const float* be2 = (const float*)d_in[13];
    const float* W3l = (const float*)d_in[14];
    const float* W3r = (const float*)d_in[15];
    const float* b3  = (const float*)d_in[16];
    float* z = (float*)d_out;

    char* ws = (char*)d_ws;
    size_t off = 0;
    auto alloc = [&](size_t bytes) -> char* {
        char* p = ws + off;
        off += (bytes + 255) & ~(size_t)255;
        return p;
    };
    int*      deg2   = (int*)alloc((size_t)N_NODES * 16 * 4);   // padded: 1 counter / 64B line; zeroed
    size_t zero_bytes = off;
    ushort_t* rank   = (ushort_t*)alloc((size_t)N_EDGES * 2);
    ushort_t* eids   = (ushort_t*)alloc((size_t)N_EDGES * 2);
    float*    scsh1g = (float*)alloc(256 * 4);
    float*    biases = (float*)alloc(512 * 4);          // bias2 + bias3l + bias3r
    int*      offs   = (int*)alloc(N_NODES * 4);
    int*      bsum   = (int*)alloc(128 * 4);
    int*      degc   = (int*)alloc(N_NODES * 4);
    float*    invd   = (float*)alloc(N_NODES * 4);
    ushort_t* xb     = (ushort_t*)alloc((size_t)N_NODES * 128 * 2);
    ushort_t* h1b    = (ushort_t*)alloc((size_t)N_NODES * 128 * 2);
    ushort_t* h2b    = (ushort_t*)alloc((size_t)N_NODES * 256 * 2);
    ushort_t* aggrb  = (ushort_t*)alloc((size_t)N_NODES * 256 * 2);   // layer-1/2 aggr; reused as t3
    ushort_t* u3b    = (ushort_t*)alloc((size_t)N_NODES * 128 * 2);
    float*    parts  = (float*)alloc((size_t)512 * GXP * 4);          // [2F][GXP], F<=256
    ushort_t* wt1l   = (ushort_t*)alloc(128 * 128 * 2);
    ushort_t* wt1r   = (ushort_t*)alloc(128 * 128 * 2);
    ushort_t* wt2l   = (ushort_t*)alloc(256 * 128 * 2);
    ushort_t* wt2r   = (ushort_t*)alloc(256 * 128 * 2);
    ushort_t* wt3l   = (ushort_t*)alloc(128 * 256 * 2);
    ushort_t* wt3r   = (ushort_t*)alloc(128 * 256 * 2);
    ushort_t* t3b    = aggrb;   // layer-3: t3 (bf16 [N,128]); aggrb free by then

    float* bias2  = biases;           // 256
    float* bias3l = biases + 256;     // 128
    float* bias3r = biases + 384;     // 128

    // CSR build: zero deg2 (3.2MB), then ONE fused dispatch (atomics || x->bf16 || W transposes)
    k_zero_i32<<<((int)(zero_bytes / 4) + 255) / 256, 256, 0, stream>>>((int*)ws, (int)(zero_bytes / 4));
    k_pre<<<6506, 256, 0, stream>>>(dst, deg2, rank, x, xb, W1l, W1r, W2l, wt1l, wt1r, wt2l);
    k_scan1<<<SCAN_NB, SCAN_BS, 0, stream>>>(deg2, offs, bsum);
    k_scan2<<<1, 128, 0, stream>>>(bsum, SCAN_NB);
    k_scan3<<<(N_NODES + 255) / 256, 256, 0, stream>>>(deg2, offs, bsum, invd, degc);
    k_fill3<<<8 * ((N_EDGES + FILL_CH - 1) / FILL_CH), 256, 0, stream>>>(src, dst, offs, rank, eids);

    const int AGG_BLKS = N_NODES / 16;        // 3125: one 16-lane group per node
    const int GEMM_G = 8 * RQ;                // 392 blocks per (colblk,outsel) variant

    // ---- Layer 1: SAGE(x) -> relu (+fused BN stats)  (K=128, F=128, YT=2)
    k_agg16<0><<<AGG_BLKS, 256, 0, stream>>>(xb, eids, offs, degc, invd, nullptr, aggrb);
    k_gemm_direct<1, 1, 1, 0, 128, 2><<<GEMM_G * 2, 256, 0, stream>>>(
        aggrb, xb, wt1l, wt1r, b1, h1b, 128, parts, nullptr, nullptr);

    // ---- Layer 2: BN1 absorbed; prep2 fuses the BN reduce  (K=128, F=256, YT=4)
    k_prep2<<<129, 256, 0, stream>>>(W2r, b2, g1, be1, parts, wt2r, bias2, scsh1g);
    k_agg16<1><<<AGG_BLKS, 256, 0, stream>>>(h1b, eids, offs, degc, invd, scsh1g, aggrb);
    k_gemm_direct<1, 1, 1, 0, 128, 4><<<GEMM_G * 4, 256, 0, stream>>>(
        aggrb, h1b, wt2l, wt2r, bias2, h2b, 256, parts, nullptr, nullptr);

    // ---- Layer 3 (commuted, BN2 absorbed; prep3 fuses the BN reduce)
    k_prep3<<<257, 256, 0, stream>>>(W3l, W3r, b3, g2, be2, parts, wt3l, wt3r, bias3l, bias3r);
    k_gemm_direct<0, 0, 0, 1, 256, 4><<<GEMM_G * 4, 256, 0, stream>>>(
        h2b, nullptr, wt3l, wt3r, bias3l, t3b, 128, nullptr, bias3r, u3b);
    k_agg_reparam<<<AGG_BLKS, 256, 0, stream>>>(t3b, eids, offs, degc, invd, u3b, eps, z);
}

// Round 13
// 275.180 us; speedup vs baseline: 1.1639x; 1.1639x over previous
//
#include <hip/hip_runtime.h>
#include <math.h>

#define N_NODES 50000
#define N_EDGES 800000
#define BN_EPS_F 1e-5f
#define SCAN_BS 512
#define SCAN_NB 98   // ceil(50000/512)
#define RC 391       // row-chunks of 128 rows
#define RQ 49        // ceil(RC/8)
#define GXP 392      // padded partials stride (>= RC)

typedef unsigned short ushort_t;
typedef unsigned int uint_t;
typedef __attribute__((ext_vector_type(8))) short bf16x8;
typedef __attribute__((ext_vector_type(4))) float f32x4;

static __device__ __forceinline__ float4 ld4(const float* p) {
    return *reinterpret_cast<const float4*>(p);
}
static __device__ __forceinline__ float bf2f(ushort_t u) {
    return __uint_as_float(((uint_t)u) << 16);
}
static __device__ __forceinline__ ushort_t f2b(float f) {
    uint_t u = __float_as_uint(f);
    u += 0x7fffu + ((u >> 16) & 1u);
    return (ushort_t)(u >> 16);
}

// ---------------- CSR build ----------------

__global__ void k_zero_i32(int* __restrict__ p, int n) {
    int i = blockIdx.x * blockDim.x + threadIdx.x;
    if (i < n) p[i] = 0;
}

// fused: countrank (even blocks; deg2 padded 1 counter/64B line) + x->bf16 (odd) + W transposes (tail)
__global__ void k_pre(const int* __restrict__ dst, int* __restrict__ deg2,
                      ushort_t* __restrict__ rank,
                      const float* __restrict__ x, ushort_t* __restrict__ xb,
                      const float* __restrict__ W1l, const float* __restrict__ W1r,
                      const float* __restrict__ W2l, ushort_t* __restrict__ wt1l,
                      ushort_t* __restrict__ wt1r, ushort_t* __restrict__ wt2l) {
    int b = blockIdx.x;
    if (b < 6250) {
        int role = b & 1;
        int id = (b >> 1) * 256 + threadIdx.x;   // < 800000 exact
        if (role == 0) {
            rank[id] = (ushort_t)atomicAdd(&deg2[dst[id] * 16], 1);
        } else {
            float4 a = ld4(x + (size_t)id * 8);
            float4 c = ld4(x + (size_t)id * 8 + 4);
            uint_t o0 = (uint_t)f2b(a.x) | ((uint_t)f2b(a.y) << 16);
            uint_t o1 = (uint_t)f2b(a.z) | ((uint_t)f2b(a.w) << 16);
            uint_t o2 = (uint_t)f2b(c.x) | ((uint_t)f2b(c.y) << 16);
            uint_t o3 = (uint_t)f2b(c.z) | ((uint_t)f2b(c.w) << 16);
            *reinterpret_cast<uint4*>(xb + (size_t)id * 8) = make_uint4(o0, o1, o2, o3);
        }
    } else {
        int idx = (b - 6250) * 256 + threadIdx.x;   // 0..65535
        if (idx < 16384) {
            int f = idx >> 7, k = idx & 127;
            wt1l[idx] = f2b(W1l[(size_t)k * 128 + f]);
        } else if (idx < 32768) {
            int j = idx - 16384;
            int f = j >> 7, k = j & 127;
            wt1r[j] = f2b(W1r[(size_t)k * 128 + f]);
        } else {
            int j = idx - 32768;                    // F=256 K=128
            int f = j >> 7, k = j & 127;
            wt2l[j] = f2b(W2l[(size_t)k * 256 + f]);
        }
    }
}

__global__ void k_scan1(const int* __restrict__ deg2, int* __restrict__ offs, int* __restrict__ bsum) {
    __shared__ int sh[SCAN_BS];
    int t = threadIdx.x;
    int g = blockIdx.x * SCAN_BS + t;
    int v = (g < N_NODES) ? deg2[g * 16] : 0;
    sh[t] = v;
    __syncthreads();
    for (int off = 1; off < SCAN_BS; off <<= 1) {
        int add = (t >= off) ? sh[t - off] : 0;
        __syncthreads();
        sh[t] += add;
        __syncthreads();
    }
    if (g < N_NODES) offs[g] = sh[t] - v;
    if (t == SCAN_BS - 1) bsum[blockIdx.x] = sh[t];
}

__global__ void k_scan2(int* __restrict__ bsum, int nb) {
    __shared__ int sh[128];
    int t = threadIdx.x;
    int v = (t < nb) ? bsum[t] : 0;
    sh[t] = v;
    __syncthreads();
    for (int off = 1; off < 128; off <<= 1) {
        int add = (t >= off) ? sh[t - off] : 0;
        __syncthreads();
        sh[t] += add;
        __syncthreads();
    }
    if (t < nb) bsum[t] = sh[t] - v;
}

__global__ void k_scan3(const int* __restrict__ deg2, int* __restrict__ offs,
                        const int* __restrict__ bsum, float* __restrict__ inv_deg,
                        int* __restrict__ degc) {
    int g = blockIdx.x * blockDim.x + threadIdx.x;
    if (g < N_NODES) {
        offs[g] += bsum[g / SCAN_BS];
        int d = deg2[g * 16];
        degc[g] = d;
        inv_deg[g] = 1.0f / (float)(d > 1 ? d : 1);
    }
}

// atomic-free scatter, ushort payload
__global__ void k_fill2(const int* __restrict__ src, const int* __restrict__ dst,
                        const int* __restrict__ offs, const ushort_t* __restrict__ rank,
                        ushort_t* __restrict__ eids) {
    int e = blockIdx.x * blockDim.x + threadIdx.x;
    if (e < N_EDGES) eids[offs[dst[e]] + (int)rank[e]] = (ushort_t)src[e];
}

// ---------------- late weight prep (need BN scsh) ----------------

__global__ void k_prep2(const float* __restrict__ W2r, const float* __restrict__ b2,
                        const float* __restrict__ scsh1, ushort_t* __restrict__ wt2r,
                        float* __restrict__ bias2) {
    int bid = blockIdx.x;
    if (bid < 128) {
        int idx = bid * 256 + threadIdx.x;      // F=256 K=128
        int f = idx >> 7, k = idx & 127;
        wt2r[idx] = f2b(scsh1[k] * W2r[(size_t)k * 256 + f]);
    } else {
        int f = threadIdx.x;
        float s = b2[f];
        for (int k = 0; k < 128; ++k) s += scsh1[128 + k] * W2r[(size_t)k * 256 + f];
        bias2[f] = s;
    }
}

__global__ void k_prep3(const float* __restrict__ W3l, const float* __restrict__ W3r,
                        const float* __restrict__ b3, const float* __restrict__ scsh2,
                        ushort_t* __restrict__ wt3l, ushort_t* __restrict__ wt3r,
                        float* __restrict__ bias3l, float* __restrict__ bias3r) {
    int bid = blockIdx.x;
    if (bid < 256) {
        int half = bid >> 7;
        int idx = (bid & 127) * 256 + threadIdx.x;   // F=128 K=256
        int f = idx >> 8, k = idx & 255;
        const float* W = half ? W3r : W3l;
        ushort_t* WT = half ? wt3r : wt3l;
        WT[idx] = f2b(scsh2[k] * W[(size_t)k * 128 + f]);
    } else {
        int t = threadIdx.x;
        int f = t & 127;
        const float* W = (t < 128) ? W3l : W3r;
        float s = (t < 128) ? 0.f : b3[f];
        for (int k = 0; k < 256; ++k) s += scsh2[256 + k] * W[(size_t)k * 128 + f];
        float* out = (t < 128) ? bias3l : bias3r;
        out[f] = s;
    }
}

// ---------------- gather core: one 16-lane GROUP per node, 8-deep pipeline ----------------

#define ACCUM8(a) do { \
    acc[0] += bf2f((ushort_t)(a).x); acc[1] += bf2f((ushort_t)((a).x >> 16)); \
    acc[2] += bf2f((ushort_t)(a).y); acc[3] += bf2f((ushort_t)((a).y >> 16)); \
    acc[4] += bf2f((ushort_t)(a).z); acc[5] += bf2f((ushort_t)((a).z >> 16)); \
    acc[6] += bf2f((ushort_t)(a).w); acc[7] += bf2f((ushort_t)((a).w >> 16)); } while (0)

static __device__ __forceinline__ void gather_rows_g(
        const ushort_t* __restrict__ h, const ushort_t* __restrict__ eids,
        int beg, int d, size_t coff, float* acc) {
    int j = 0;
    for (; j + 8 <= d; j += 8) {
        uint4 a[8];
#pragma unroll
        for (int k = 0; k < 8; ++k) {
            int s = eids[beg + j + k];
            a[k] = *reinterpret_cast<const uint4*>(h + (size_t)s * 128 + coff);
        }
#pragma unroll
        for (int k = 0; k < 8; ++k) ACCUM8(a[k]);
    }
    for (; j + 4 <= d; j += 4) {
        uint4 a[4];
#pragma unroll
        for (int k = 0; k < 4; ++k) {
            int s = eids[beg + j + k];
            a[k] = *reinterpret_cast<const uint4*>(h + (size_t)s * 128 + coff);
        }
#pragma unroll
        for (int k = 0; k < 4; ++k) ACCUM8(a[k]);
    }
    for (; j + 2 <= d; j += 2) {
        int s0 = eids[beg + j];
        int s1 = eids[beg + j + 1];
        uint4 a = *reinterpret_cast<const uint4*>(h + (size_t)s0 * 128 + coff);
        uint4 b = *reinterpret_cast<const uint4*>(h + (size_t)s1 * 128 + coff);
        ACCUM8(a); ACCUM8(b);
    }
    if (j < d) {
        int s0 = eids[beg + j];
        uint4 a = *reinterpret_cast<const uint4*>(h + (size_t)s0 * 128 + coff);
        ACCUM8(a);
    }
}

template<int BN>
__global__ __launch_bounds__(256) void k_agg16(
        const ushort_t* __restrict__ h, const ushort_t* __restrict__ eids,
        const int* __restrict__ offs, const int* __restrict__ deg,
        const float* __restrict__ inv_deg, const float* __restrict__ scsh,
        ushort_t* __restrict__ out) {
    const int node = blockIdx.x * 16 + (threadIdx.x >> 4);
    const int lr = threadIdx.x & 15;
    if (node >= N_NODES) return;
    float acc[8];
#pragma unroll
    for (int v = 0; v < 8; ++v) acc[v] = 0.f;
    const int beg = offs[node];
    const int d = deg[node];
    const size_t coff = (size_t)lr * 8;
    gather_rows_g(h, eids, beg, d, coff, acc);

    float sc = inv_deg[node];
    if (BN) {
        float4 sa0 = ld4(&scsh[lr * 8]), sa1 = ld4(&scsh[lr * 8 + 4]);
        float4 sb0 = ld4(&scsh[128 + lr * 8]), sb1 = ld4(&scsh[128 + lr * 8 + 4]);
        if (d > 0) {
            acc[0] = acc[0] * sc * sa0.x + sb0.x; acc[1] = acc[1] * sc * sa0.y + sb0.y;
            acc[2] = acc[2] * sc * sa0.z + sb0.z; acc[3] = acc[3] * sc * sa0.w + sb0.w;
            acc[4] = acc[4] * sc * sa1.x + sb1.x; acc[5] = acc[5] * sc * sa1.y + sb1.y;
            acc[6] = acc[6] * sc * sa1.z + sb1.z; acc[7] = acc[7] * sc * sa1.w + sb1.w;
        } else {
#pragma unroll
            for (int v = 0; v < 8; ++v) acc[v] = 0.f;
        }
    } else {
#pragma unroll
        for (int v = 0; v < 8; ++v) acc[v] *= sc;
    }
    uint4 o;
    o.x = (uint_t)f2b(acc[0]) | ((uint_t)f2b(acc[1]) << 16);
    o.y = (uint_t)f2b(acc[2]) | ((uint_t)f2b(acc[3]) << 16);
    o.z = (uint_t)f2b(acc[4]) | ((uint_t)f2b(acc[5]) << 16);
    o.w = (uint_t)f2b(acc[6]) | ((uint_t)f2b(acc[7]) << 16);
    *reinterpret_cast<uint4*>(out + (size_t)node * 128 + coff) = o;
}

__global__ __launch_bounds__(256) void k_agg_reparam(
        const ushort_t* __restrict__ t3, const ushort_t* __restrict__ eids,
        const int* __restrict__ offs, const int* __restrict__ deg,
        const float* __restrict__ inv_deg, const ushort_t* __restrict__ u,
        const float* __restrict__ eps, float* __restrict__ z) {
    const int node = blockIdx.x * 16 + (threadIdx.x >> 4);
    const int lr = threadIdx.x & 15;
    if (node >= N_NODES) return;
    float acc[8];
#pragma unroll
    for (int v = 0; v < 8; ++v) acc[v] = 0.f;
    const int beg = offs[node];
    const int d = deg[node];
    const size_t coff = (size_t)lr * 8;
    gather_rows_g(t3, eids, beg, d, coff, acc);
    float ls[8];
#pragma unroll
    for (int v = 0; v < 8; ++v) ls[v] = __shfl_down(acc[v], 8);

    if (lr < 8) {
        float sc = inv_deg[node];
        uint4 um4 = *reinterpret_cast<const uint4*>(u + (size_t)node * 128 + lr * 8);
        uint4 ul4 = *reinterpret_cast<const uint4*>(u + (size_t)node * 128 + 64 + lr * 8);
        const float* ep = eps + (size_t)node * 64 + lr * 8;
        float4 e0 = ld4(ep), e1 = ld4(ep + 4);
        float um[8], ul[8];
        um[0] = bf2f((ushort_t)um4.x); um[1] = bf2f((ushort_t)(um4.x >> 16));
        um[2] = bf2f((ushort_t)um4.y); um[3] = bf2f((ushort_t)(um4.y >> 16));
        um[4] = bf2f((ushort_t)um4.z); um[5] = bf2f((ushort_t)(um4.z >> 16));
        um[6] = bf2f((ushort_t)um4.w); um[7] = bf2f((ushort_t)(um4.w >> 16));
        ul[0] = bf2f((ushort_t)ul4.x); ul[1] = bf2f((ushort_t)(ul4.x >> 16));
        ul[2] = bf2f((ushort_t)ul4.y); ul[3] = bf2f((ushort_t)(ul4.y >> 16));
        ul[4] = bf2f((ushort_t)ul4.z); ul[5] = bf2f((ushort_t)(ul4.z >> 16));
        ul[6] = bf2f((ushort_t)ul4.w); ul[7] = bf2f((ushort_t)(ul4.w >> 16));
        float4 o0, o1;
        o0.x = (acc[0] * sc + um[0]) + expf(ls[0] * sc + ul[0]) * e0.x;
        o0.y = (acc[1] * sc + um[1]) + expf(ls[1] * sc + ul[1]) * e0.y;
        o0.z = (acc[2] * sc + um[2]) + expf(ls[2] * sc + ul[2]) * e0.z;
        o0.w = (acc[3] * sc + um[3]) + expf(ls[3] * sc + ul[3]) * e0.w;
        o1.x = (acc[4] * sc + um[4]) + expf(ls[4] * sc + ul[4]) * e1.x;
        o1.y = (acc[5] * sc + um[5]) + expf(ls[5] * sc + ul[5]) * e1.y;
        o1.z = (acc[6] * sc + um[6]) + expf(ls[6] * sc + ul[6]) * e1.z;
        o1.w = (acc[7] * sc + um[7]) + expf(ls[7] * sc + ul[7]) * e1.w;
        float* zp = z + (size_t)node * 64 + lr * 8;
        *reinterpret_cast<float4*>(zp) = o0;
        *reinterpret_cast<float4*>(zp + 4) = o1;
    }
}

// ---------------- direct-fragment MFMA GEMM, ping-pong register pipeline ----------------
// Block: 4 waves stacked on rows -> 128 rows x 64 cols; wave tile 32x64 (acc 2x4).
// Chunk = 64 K-columns = 12 x 16B loads (4 A-frag + 8 B-frag). Two register
// buffers; chunk c+2's loads issue BEFORE chunk c's MFMAs retire -> counted
// vmcnt, latency overlapped. NC=4 chunks for all layers (DUAL: 2 mat x 2
// chunks; else K=256: 4 chunks). XCD-class decode; no launch_bounds clamp.

template<int RELU, int DUAL, int STATS, int SEL3, int K>
__global__ __launch_bounds__(256) void k_gemm_pp(
        const ushort_t* __restrict__ A1, const ushort_t* __restrict__ A2,
        const ushort_t* __restrict__ B1, const ushort_t* __restrict__ B2,
        const float* __restrict__ bias, ushort_t* __restrict__ out,
        int F, float* __restrict__ partials,
        const float* __restrict__ bias2, ushort_t* __restrict__ out2) {
    const int bid = blockIdx.x;
    const int grp = bid >> 3;
    const int y = grp / RQ;
    const int rq = grp - y * RQ;
    const int r = (bid & 7) + (rq << 3);
    if (r >= RC) return;
    const int row0 = r * 128;

    int colblk = y, outsel = 0;
    if (SEL3) { colblk = y & 1; outsel = y >> 1; }
    const int col0 = colblk * 64;
    const ushort_t* __restrict__ Bp = (SEL3 && outsel) ? B2 : B1;
    const float* __restrict__ biasp = (SEL3 && outsel) ? bias2 : bias;
    ushort_t* __restrict__ outp = (SEL3 && outsel) ? out2 : out;

    const int tid = threadIdx.x;
    const int lane = tid & 63;
    const int w = tid >> 6;
    const int q = lane >> 4, lr = lane & 15;
    const int wrow = row0 + w * 32;             // wave's 32-row strip

    // per-lane base element-offsets
    size_t aoffr[2];
#pragma unroll
    for (int rf = 0; rf < 2; ++rf) {
        int rr = wrow + rf * 16 + lr;
        if (rr > N_NODES - 1) rr = N_NODES - 1;
        aoffr[rf] = (size_t)rr * K + q * 8;
    }
    size_t boffc[4];
#pragma unroll
    for (int cf = 0; cf < 4; ++cf)
        boffc[cf] = (size_t)(col0 + cf * 16 + lr) * K + q * 8;

    f32x4 acc[2][4];
#pragma unroll
    for (int mf = 0; mf < 2; ++mf)
#pragma unroll
        for (int nf = 0; nf < 4; ++nf)
            acc[mf][nf] = (f32x4){0.f, 0.f, 0.f, 0.f};

    bf16x8 av0[2][2], bv0[2][4], av1[2][2], bv1[2][4];   // [k0][frag]

#define LOADCH(AV, BV, CI) do {                                              \
    const ushort_t* MA_ = (DUAL && (CI) >= 2) ? A2 : A1;                     \
    const ushort_t* MB_ = (DUAL && (CI) >= 2) ? B2 : Bp;                     \
    const int kb_ = DUAL ? (((CI) & 1) * 64) : ((CI) * 64);                  \
    _Pragma("unroll")                                                        \
    for (int k0 = 0; k0 < 2; ++k0) {                                         \
        _Pragma("unroll")                                                    \
        for (int rf = 0; rf < 2; ++rf)                                       \
            AV[k0][rf] = *reinterpret_cast<const bf16x8*>(                   \
                MA_ + aoffr[rf] + kb_ + k0 * 32);                            \
        _Pragma("unroll")                                                    \
        for (int cf = 0; cf < 4; ++cf)                                       \
            BV[k0][cf] = *reinterpret_cast<const bf16x8*>(                   \
                MB_ + boffc[cf] + kb_ + k0 * 32);                            \
    } } while (0)

#define MMCH(AV, BV) do {                                                    \
    _Pragma("unroll")                                                        \
    for (int k0 = 0; k0 < 2; ++k0)                                           \
        _Pragma("unroll")                                                    \
        for (int mf = 0; mf < 2; ++mf)                                       \
            _Pragma("unroll")                                                \
            for (int nf = 0; nf < 4; ++nf)                                   \
                acc[mf][nf] = __builtin_amdgcn_mfma_f32_16x16x32_bf16(       \
                    AV[k0][mf], BV[k0][nf], acc[mf][nf], 0, 0, 0);           \
    } while (0)

    LOADCH(av0, bv0, 0);
    LOADCH(av1, bv1, 1);
    MMCH(av0, bv0);
    LOADCH(av0, bv0, 2);
    MMCH(av1, bv1);
    LOADCH(av1, bv1, 3);
    MMCH(av0, bv0);
    MMCH(av1, bv1);

#undef LOADCH
#undef MMCH

    // ---- epilogue: bias/relu/stats in regs, LDS transpose, coalesced 16B stores
    __shared__ __align__(16) short lw[4][32][72];     // 18432 B
    __shared__ float sdf[2][16][64];                  // 8192 B

    float s[4], s2[4];
#pragma unroll
    for (int nf = 0; nf < 4; ++nf) { s[nf] = 0.f; s2[nf] = 0.f; }
#pragma unroll
    for (int nf = 0; nf < 4; ++nf) {
        float bvs = biasp[col0 + nf * 16 + lr];
#pragma unroll
        for (int mf = 0; mf < 2; ++mf) {
#pragma unroll
            for (int b = 0; b < 4; ++b) {
                int rloc = mf * 16 + q * 4 + b;       // row within wave strip
                float v = acc[mf][nf][b] + bvs;
                if (RELU) v = fmaxf(v, 0.f);
                if (STATS && (wrow + rloc) < N_NODES) { s[nf] += v; s2[nf] += v * v; }
                lw[w][rloc][nf * 16 + lr] = (short)f2b(v);
            }
        }
    }
    // same-wave LDS readback (compiler inserts lgkmcnt wait)
#pragma unroll
    for (int it = 0; it < 4; ++it) {
        int row = it * 8 + (lane >> 3);
        int gr = wrow + row;
        if (gr < N_NODES) {
            uint4 vv = *reinterpret_cast<const uint4*>(&lw[w][row][(lane & 7) * 8]);
            *reinterpret_cast<uint4*>(outp + (size_t)gr * F + col0 + (lane & 7) * 8) = vv;
        }
    }

    if constexpr (STATS) {
        const int u = w * 4 + q;                      // 16 contributors per col
#pragma unroll
        for (int nf = 0; nf < 4; ++nf) {
            sdf[0][u][nf * 16 + lr] = s[nf];
            sdf[1][u][nf * 16 + lr] = s2[nf];
        }
        __syncthreads();
        if (tid < 64) {
            float ss = 0.f, qq = 0.f;
#pragma unroll
            for (int u2 = 0; u2 < 16; ++u2) {
                ss += sdf[0][u2][tid];
                qq += sdf[1][u2][tid];
            }
            int cg = col0 + tid;
            partials[(size_t)cg * GXP + r] = ss;
            partials[(size_t)(F + cg) * GXP + r] = qq;
        }
    }
}

// ---------------- BN: reduce partials -> scale/shift ----------------

template<int F>
__global__ __launch_bounds__(64) void k_bn_scsh(
        const float* __restrict__ partials, const float* __restrict__ gamma,
        const float* __restrict__ beta, float* __restrict__ scsh) {
    const int c = blockIdx.x;
    const int l = threadIdx.x;
    float s = 0.f, q2 = 0.f;
    for (int g = l; g < RC; g += 64) {
        s += partials[(size_t)c * GXP + g];
        q2 += partials[(size_t)(F + c) * GXP + g];
    }
#pragma unroll
    for (int off = 1; off < 64; off <<= 1) {
        s += __shfl_xor(s, off);
        q2 += __shfl_xor(q2, off);
    }
    if (l == 0) {
        float mean = s * (1.0f / N_NODES);
        float var = q2 * (1.0f / N_NODES) - mean * mean;
        float sc = gamma[c] * rsqrtf(var + BN_EPS_F);
        scsh[c] = sc;
        scsh[F + c] = beta[c] - mean * sc;
    }
}

// ---------------- launch ----------------

extern "C" void kernel_launch(void* const* d_in, const int* in_sizes, int n_in,
                              void* d_out, int out_size, void* d_ws, size_t ws_size,
                              hipStream_t stream) {
    (void)in_sizes; (void)n_in; (void)out_size; (void)ws_size;
    const float* x   = (const float*)d_in[0];
    const int*   src = (const int*)d_in[1];
    const int*   dst = (const int*)d_in[2];
    const float* eps = (const float*)d_in[3];
    const float* W1l = (const float*)d_in[4];
    const float* W1r = (const float*)d_in[5];
    const float* b1  = (const float*)d_in[6];
    const float* g1  = (const float*)d_in[7];
    const float* be1 = (const float*)d_in[8];
    const float* W2l = (const float*)d_in[9];
    const float* W2r = (const float*)d_in[10];
    const float* b2  = (const float*)d_in[11];
    const float* g2  = (const float*)d_in[12];
    const float* be2 = (const float*)d_in[13];
    const float* W3l = (const float*)d_in[14];
    const float* W3r = (const float*)d_in[15];
    const float* b3  = (const float*)d_in[16];
    float* z = (float*)d_out;

    char* ws = (char*)d_ws;
    size_t off = 0;
    auto alloc = [&](size_t bytes) -> char* {
        char* p = ws + off;
        off += (bytes + 255) & ~(size_t)255;
        return p;
    };
    int*      deg2   = (int*)alloc((size_t)N_NODES * 16 * 4);   // padded: 1 counter / 64B line; zeroed
    size_t zero_bytes = off;
    ushort_t* rank   = (ushort_t*)alloc((size_t)N_EDGES * 2);
    ushort_t* eids   = (ushort_t*)alloc((size_t)N_EDGES * 2);
    float*    scshs  = (float*)alloc(1024 * 4);         // scsh1 (256) + scsh2 (512)
    float*    biases = (float*)alloc(512 * 4);          // bias2 + bias3l + bias3r
    int*      offs   = (int*)alloc(N_NODES * 4);
    int*      bsum   = (int*)alloc(128 * 4);
    int*      degc   = (int*)alloc(N_NODES * 4);
    float*    invd   = (float*)alloc(N_NODES * 4);
    ushort_t* xb     = (ushort_t*)alloc((size_t)N_NODES * 128 * 2);
    ushort_t* h1b    = (ushort_t*)alloc((size_t)N_NODES * 128 * 2);
    ushort_t* h2b    = (ushort_t*)alloc((size_t)N_NODES * 256 * 2);
    ushort_t* aggrb  = (ushort_t*)alloc((size_t)N_NODES * 256 * 2);   // layer-1/2 aggr; reused as t3
    ushort_t* u3b    = (ushort_t*)alloc((size_t)N_NODES * 128 * 2);
    float*    parts  = (float*)alloc((size_t)512 * GXP * 4);          // [2F][GXP], F<=256
    ushort_t* wt1l   = (ushort_t*)alloc(128 * 128 * 2);
    ushort_t* wt1r   = (ushort_t*)alloc(128 * 128 * 2);
    ushort_t* wt2l   = (ushort_t*)alloc(256 * 128 * 2);
    ushort_t* wt2r   = (ushort_t*)alloc(256 * 128 * 2);
    ushort_t* wt3l   = (ushort_t*)alloc(128 * 256 * 2);
    ushort_t* wt3r   = (ushort_t*)alloc(128 * 256 * 2);
    ushort_t* t3b    = aggrb;   // layer-3: t3 (bf16 [N,128]); aggrb free by then

    float* scsh1  = scshs;            // [sc1(128) | sh1(128)]
    float* scsh2  = scshs + 256;      // [sc2(256) | sh2(256)]
    float* bias2  = biases;           // 256
    float* bias3l = biases + 256;     // 128
    float* bias3r = biases + 384;     // 128

    // CSR build: zero deg2 (3.2MB), then ONE fused dispatch (atomics || x->bf16 || W transposes)
    k_zero_i32<<<((int)(zero_bytes / 4) + 255) / 256, 256, 0, stream>>>((int*)ws, (int)(zero_bytes / 4));
    k_pre<<<6506, 256, 0, stream>>>(dst, deg2, rank, x, xb, W1l, W1r, W2l, wt1l, wt1r, wt2l);
    k_scan1<<<SCAN_NB, SCAN_BS, 0, stream>>>(deg2, offs, bsum);
    k_scan2<<<1, 128, 0, stream>>>(bsum, SCAN_NB);
    k_scan3<<<(N_NODES + 255) / 256, 256, 0, stream>>>(deg2, offs, bsum, invd, degc);
    k_fill2<<<(N_EDGES + 255) / 256, 256, 0, stream>>>(src, dst, offs, rank, eids);

    const int AGG_BLKS = N_NODES / 16;        // 3125: one 16-lane group per node
    const int GEMM_G = 8 * RQ;                // 392 blocks per (colblk,outsel) variant

    // ---- Layer 1: SAGE(x) -> relu (+fused BN stats)  (K=128, 2 colblocks)
    k_agg16<0><<<AGG_BLKS, 256, 0, stream>>>(xb, eids, offs, degc, invd, nullptr, aggrb);
    k_gemm_pp<1, 1, 1, 0, 128><<<GEMM_G * 2, 256, 0, stream>>>(
        aggrb, xb, wt1l, wt1r, b1, h1b, 128, parts, nullptr, nullptr);
    k_bn_scsh<128><<<128, 64, 0, stream>>>(parts, g1, be1, scsh1);

    // ---- Layer 2: BN1 absorbed (agg-side fused, self-side in wt2r/bias2)  (K=128, 4 colblocks)
    k_prep2<<<129, 256, 0, stream>>>(W2r, b2, scsh1, wt2r, bias2);
    k_agg16<1><<<AGG_BLKS, 256, 0, stream>>>(h1b, eids, offs, degc, invd, scsh1, aggrb);
    k_gemm_pp<1, 1, 1, 0, 128><<<GEMM_G * 4, 256, 0, stream>>>(
        aggrb, h1b, wt2l, wt2r, bias2, h2b, 256, parts, nullptr, nullptr);
    k_bn_scsh<256><<<256, 64, 0, stream>>>(parts, g2, be2, scsh2);

    // ---- Layer 3 (commuted, BN2 absorbed): ONE dispatch, SEL3 picks output
    //      outsel=0: t3 = h2@wt3l' + bias3l; outsel=1: u3 = h2@wt3r' + bias3r
    k_prep3<<<257, 256, 0, stream>>>(W3l, W3r, b3, scsh2, wt3l, wt3r, bias3l, bias3r);
    k_gemm_pp<0, 0, 0, 1, 256><<<GEMM_G * 4, 256, 0, stream>>>(
        h2b, nullptr, wt3l, wt3r, bias3l, t3b, 128, nullptr, bias3r, u3b);
    k_agg_reparam<<<AGG_BLKS, 256, 0, stream>>>(t3b, eids, offs, degc, invd, u3b, eps, z);
}

// Round 14
// 274.714 us; speedup vs baseline: 1.1659x; 1.0017x over previous
//
#include <hip/hip_runtime.h>
#include <math.h>

#define N_NODES 50000
#define N_EDGES 800000
#define BN_EPS_F 1e-5f
#define SCAN_BS 512
#define SCAN_NB 98   // ceil(50000/512)
#define RC 391       // row-chunks of 128 rows
#define RQ 49        // ceil(RC/8)
#define GXP 392      // padded partials stride (>= RC)

typedef unsigned short ushort_t;
typedef unsigned int uint_t;
typedef __attribute__((ext_vector_type(8))) short bf16x8;
typedef __attribute__((ext_vector_type(4))) float f32x4;

static __device__ __forceinline__ float4 ld4(const float* p) {
    return *reinterpret_cast<const float4*>(p);
}
static __device__ __forceinline__ float bf2f(ushort_t u) {
    return __uint_as_float(((uint_t)u) << 16);
}
static __device__ __forceinline__ ushort_t f2b(float f) {
    uint_t u = __float_as_uint(f);
    u += 0x7fffu + ((u >> 16) & 1u);
    return (ushort_t)(u >> 16);
}

// ---------------- CSR build ----------------

__global__ void k_zero_i32(int* __restrict__ p, int n) {
    int i = blockIdx.x * blockDim.x + threadIdx.x;
    if (i < n) p[i] = 0;
}

// fused: countrank (even blocks; deg2 padded 1 counter/64B line) + x->bf16 (odd) + W transposes (tail)
__global__ void k_pre(const int* __restrict__ dst, int* __restrict__ deg2,
                      ushort_t* __restrict__ rank,
                      const float* __restrict__ x, ushort_t* __restrict__ xb,
                      const float* __restrict__ W1l, const float* __restrict__ W1r,
                      const float* __restrict__ W2l, ushort_t* __restrict__ wt1l,
                      ushort_t* __restrict__ wt1r, ushort_t* __restrict__ wt2l) {
    int b = blockIdx.x;
    if (b < 6250) {
        int role = b & 1;
        int id = (b >> 1) * 256 + threadIdx.x;   // < 800000 exact
        if (role == 0) {
            rank[id] = (ushort_t)atomicAdd(&deg2[dst[id] * 16], 1);
        } else {
            float4 a = ld4(x + (size_t)id * 8);
            float4 c = ld4(x + (size_t)id * 8 + 4);
            uint_t o0 = (uint_t)f2b(a.x) | ((uint_t)f2b(a.y) << 16);
            uint_t o1 = (uint_t)f2b(a.z) | ((uint_t)f2b(a.w) << 16);
            uint_t o2 = (uint_t)f2b(c.x) | ((uint_t)f2b(c.y) << 16);
            uint_t o3 = (uint_t)f2b(c.z) | ((uint_t)f2b(c.w) << 16);
            *reinterpret_cast<uint4*>(xb + (size_t)id * 8) = make_uint4(o0, o1, o2, o3);
        }
    } else {
        int idx = (b - 6250) * 256 + threadIdx.x;   // 0..65535
        if (idx < 16384) {
            int f = idx >> 7, k = idx & 127;
            wt1l[idx] = f2b(W1l[(size_t)k * 128 + f]);
        } else if (idx < 32768) {
            int j = idx - 16384;
            int f = j >> 7, k = j & 127;
            wt1r[j] = f2b(W1r[(size_t)k * 128 + f]);
        } else {
            int j = idx - 32768;                    // F=256 K=128
            int f = j >> 7, k = j & 127;
            wt2l[j] = f2b(W2l[(size_t)k * 256 + f]);
        }
    }
}

__global__ void k_scan1(const int* __restrict__ deg2, int* __restrict__ offs, int* __restrict__ bsum) {
    __shared__ int sh[SCAN_BS];
    int t = threadIdx.x;
    int g = blockIdx.x * SCAN_BS + t;
    int v = (g < N_NODES) ? deg2[g * 16] : 0;
    sh[t] = v;
    __syncthreads();
    for (int off = 1; off < SCAN_BS; off <<= 1) {
        int add = (t >= off) ? sh[t - off] : 0;
        __syncthreads();
        sh[t] += add;
        __syncthreads();
    }
    if (g < N_NODES) offs[g] = sh[t] - v;
    if (t == SCAN_BS - 1) bsum[blockIdx.x] = sh[t];
}

__global__ void k_scan2(int* __restrict__ bsum, int nb) {
    __shared__ int sh[128];
    int t = threadIdx.x;
    int v = (t < nb) ? bsum[t] : 0;
    sh[t] = v;
    __syncthreads();
    for (int off = 1; off < 128; off <<= 1) {
        int add = (t >= off) ? sh[t - off] : 0;
        __syncthreads();
        sh[t] += add;
        __syncthreads();
    }
    if (t < nb) bsum[t] = sh[t] - v;
}

__global__ void k_scan3(const int* __restrict__ deg2, int* __restrict__ offs,
                        const int* __restrict__ bsum, float* __restrict__ inv_deg,
                        int* __restrict__ degc) {
    int g = blockIdx.x * blockDim.x + threadIdx.x;
    if (g < N_NODES) {
        offs[g] += bsum[g / SCAN_BS];
        int d = deg2[g * 16];
        degc[g] = d;
        inv_deg[g] = 1.0f / (float)(d > 1 ? d : 1);
    }
}

// atomic-free scatter, ushort payload
__global__ void k_fill2(const int* __restrict__ src, const int* __restrict__ dst,
                        const int* __restrict__ offs, const ushort_t* __restrict__ rank,
                        ushort_t* __restrict__ eids) {
    int e = blockIdx.x * blockDim.x + threadIdx.x;
    if (e < N_EDGES) eids[offs[dst[e]] + (int)rank[e]] = (ushort_t)src[e];
}

// ---------------- late weight prep (need BN scsh) ----------------

__global__ void k_prep2(const float* __restrict__ W2r, const float* __restrict__ b2,
                        const float* __restrict__ scsh1, ushort_t* __restrict__ wt2r,
                        float* __restrict__ bias2) {
    int bid = blockIdx.x;
    if (bid < 128) {
        int idx = bid * 256 + threadIdx.x;      // F=256 K=128
        int f = idx >> 7, k = idx & 127;
        wt2r[idx] = f2b(scsh1[k] * W2r[(size_t)k * 256 + f]);
    } else {
        int f = threadIdx.x;
        float s = b2[f];
        for (int k = 0; k < 128; ++k) s += scsh1[128 + k] * W2r[(size_t)k * 256 + f];
        bias2[f] = s;
    }
}

__global__ void k_prep3(const float* __restrict__ W3l, const float* __restrict__ W3r,
                        const float* __restrict__ b3, const float* __restrict__ scsh2,
                        ushort_t* __restrict__ wt3l, ushort_t* __restrict__ wt3r,
                        float* __restrict__ bias3l, float* __restrict__ bias3r) {
    int bid = blockIdx.x;
    if (bid < 256) {
        int half = bid >> 7;
        int idx = (bid & 127) * 256 + threadIdx.x;   // F=128 K=256
        int f = idx >> 8, k = idx & 255;
        const float* W = half ? W3r : W3l;
        ushort_t* WT = half ? wt3r : wt3l;
        WT[idx] = f2b(scsh2[k] * W[(size_t)k * 128 + f]);
    } else {
        int t = threadIdx.x;
        int f = t & 127;
        const float* W = (t < 128) ? W3l : W3r;
        float s = (t < 128) ? 0.f : b3[f];
        for (int k = 0; k < 256; ++k) s += scsh2[256 + k] * W[(size_t)k * 128 + f];
        float* out = (t < 128) ? bias3l : bias3r;
        out[f] = s;
    }
}

// ---------------- gather core: one 16-lane GROUP per node, 8-deep pipeline ----------------

#define ACCUM8(a) do { \
    acc[0] += bf2f((ushort_t)(a).x); acc[1] += bf2f((ushort_t)((a).x >> 16)); \
    acc[2] += bf2f((ushort_t)(a).y); acc[3] += bf2f((ushort_t)((a).y >> 16)); \
    acc[4] += bf2f((ushort_t)(a).z); acc[5] += bf2f((ushort_t)((a).z >> 16)); \
    acc[6] += bf2f((ushort_t)(a).w); acc[7] += bf2f((ushort_t)((a).w >> 16)); } while (0)

static __device__ __forceinline__ void gather_rows_g(
        const ushort_t* __restrict__ h, const ushort_t* __restrict__ eids,
        int beg, int d, size_t coff, float* acc) {
    int j = 0;
    for (; j + 8 <= d; j += 8) {
        uint4 a[8];
#pragma unroll
        for (int k = 0; k < 8; ++k) {
            int s = eids[beg + j + k];
            a[k] = *reinterpret_cast<const uint4*>(h + (size_t)s * 128 + coff);
        }
#pragma unroll
        for (int k = 0; k < 8; ++k) ACCUM8(a[k]);
    }
    for (; j + 4 <= d; j += 4) {
        uint4 a[4];
#pragma unroll
        for (int k = 0; k < 4; ++k) {
            int s = eids[beg + j + k];
            a[k] = *reinterpret_cast<const uint4*>(h + (size_t)s * 128 + coff);
        }
#pragma unroll
        for (int k = 0; k < 4; ++k) ACCUM8(a[k]);
    }
    for (; j + 2 <= d; j += 2) {
        int s0 = eids[beg + j];
        int s1 = eids[beg + j + 1];
        uint4 a = *reinterpret_cast<const uint4*>(h + (size_t)s0 * 128 + coff);
        uint4 b = *reinterpret_cast<const uint4*>(h + (size_t)s1 * 128 + coff);
        ACCUM8(a); ACCUM8(b);
    }
    if (j < d) {
        int s0 = eids[beg + j];
        uint4 a = *reinterpret_cast<const uint4*>(h + (size_t)s0 * 128 + coff);
        ACCUM8(a);
    }
}

template<int BN>
__global__ __launch_bounds__(256) void k_agg16(
        const ushort_t* __restrict__ h, const ushort_t* __restrict__ eids,
        const int* __restrict__ offs, const int* __restrict__ deg,
        const float* __restrict__ inv_deg, const float* __restrict__ scsh,
        ushort_t* __restrict__ out) {
    const int node = blockIdx.x * 16 + (threadIdx.x >> 4);
    const int lr = threadIdx.x & 15;
    if (node >= N_NODES) return;
    float acc[8];
#pragma unroll
    for (int v = 0; v < 8; ++v) acc[v] = 0.f;
    const int beg = offs[node];
    const int d = deg[node];
    const size_t coff = (size_t)lr * 8;
    gather_rows_g(h, eids, beg, d, coff, acc);

    float sc = inv_deg[node];
    if (BN) {
        float4 sa0 = ld4(&scsh[lr * 8]), sa1 = ld4(&scsh[lr * 8 + 4]);
        float4 sb0 = ld4(&scsh[128 + lr * 8]), sb1 = ld4(&scsh[128 + lr * 8 + 4]);
        if (d > 0) {
            acc[0] = acc[0] * sc * sa0.x + sb0.x; acc[1] = acc[1] * sc * sa0.y + sb0.y;
            acc[2] = acc[2] * sc * sa0.z + sb0.z; acc[3] = acc[3] * sc * sa0.w + sb0.w;
            acc[4] = acc[4] * sc * sa1.x + sb1.x; acc[5] = acc[5] * sc * sa1.y + sb1.y;
            acc[6] = acc[6] * sc * sa1.z + sb1.z; acc[7] = acc[7] * sc * sa1.w + sb1.w;
        } else {
#pragma unroll
            for (int v = 0; v < 8; ++v) acc[v] = 0.f;
        }
    } else {
#pragma unroll
        for (int v = 0; v < 8; ++v) acc[v] *= sc;
    }
    uint4 o;
    o.x = (uint_t)f2b(acc[0]) | ((uint_t)f2b(acc[1]) << 16);
    o.y = (uint_t)f2b(acc[2]) | ((uint_t)f2b(acc[3]) << 16);
    o.z = (uint_t)f2b(acc[4]) | ((uint_t)f2b(acc[5]) << 16);
    o.w = (uint_t)f2b(acc[6]) | ((uint_t)f2b(acc[7]) << 16);
    *reinterpret_cast<uint4*>(out + (size_t)node * 128 + coff) = o;
}

__global__ __launch_bounds__(256) void k_agg_reparam(
        const ushort_t* __restrict__ t3, const ushort_t* __restrict__ eids,
        const int* __restrict__ offs, const int* __restrict__ deg,
        const float* __restrict__ inv_deg, const ushort_t* __restrict__ u,
        const float* __restrict__ eps, float* __restrict__ z) {
    const int node = blockIdx.x * 16 + (threadIdx.x >> 4);
    const int lr = threadIdx.x & 15;
    if (node >= N_NODES) return;
    float acc[8];
#pragma unroll
    for (int v = 0; v < 8; ++v) acc[v] = 0.f;
    const int beg = offs[node];
    const int d = deg[node];
    const size_t coff = (size_t)lr * 8;
    gather_rows_g(t3, eids, beg, d, coff, acc);
    float ls[8];
#pragma unroll
    for (int v = 0; v < 8; ++v) ls[v] = __shfl_down(acc[v], 8);

    if (lr < 8) {
        float sc = inv_deg[node];
        uint4 um4 = *reinterpret_cast<const uint4*>(u + (size_t)node * 128 + lr * 8);
        uint4 ul4 = *reinterpret_cast<const uint4*>(u + (size_t)node * 128 + 64 + lr * 8);
        const float* ep = eps + (size_t)node * 64 + lr * 8;
        float4 e0 = ld4(ep), e1 = ld4(ep + 4);
        float um[8], ul[8];
        um[0] = bf2f((ushort_t)um4.x); um[1] = bf2f((ushort_t)(um4.x >> 16));
        um[2] = bf2f((ushort_t)um4.y); um[3] = bf2f((ushort_t)(um4.y >> 16));
        um[4] = bf2f((ushort_t)um4.z); um[5] = bf2f((ushort_t)(um4.z >> 16));
        um[6] = bf2f((ushort_t)um4.w); um[7] = bf2f((ushort_t)(um4.w >> 16));
        ul[0] = bf2f((ushort_t)ul4.x); ul[1] = bf2f((ushort_t)(ul4.x >> 16));
        ul[2] = bf2f((ushort_t)ul4.y); ul[3] = bf2f((ushort_t)(ul4.y >> 16));
        ul[4] = bf2f((ushort_t)ul4.z); ul[5] = bf2f((ushort_t)(ul4.z >> 16));
        ul[6] = bf2f((ushort_t)ul4.w); ul[7] = bf2f((ushort_t)(ul4.w >> 16));
        float4 o0, o1;
        o0.x = (acc[0] * sc + um[0]) + expf(ls[0] * sc + ul[0]) * e0.x;
        o0.y = (acc[1] * sc + um[1]) + expf(ls[1] * sc + ul[1]) * e0.y;
        o0.z = (acc[2] * sc + um[2]) + expf(ls[2] * sc + ul[2]) * e0.z;
        o0.w = (acc[3] * sc + um[3]) + expf(ls[3] * sc + ul[3]) * e0.w;
        o1.x = (acc[4] * sc + um[4]) + expf(ls[4] * sc + ul[4]) * e1.x;
        o1.y = (acc[5] * sc + um[5]) + expf(ls[5] * sc + ul[5]) * e1.y;
        o1.z = (acc[6] * sc + um[6]) + expf(ls[6] * sc + ul[6]) * e1.z;
        o1.w = (acc[7] * sc + um[7]) + expf(ls[7] * sc + ul[7]) * e1.w;
        float* zp = z + (size_t)node * 64 + lr * 8;
        *reinterpret_cast<float4*>(zp) = o0;
        *reinterpret_cast<float4*>(zp + 4) = o1;
    }
}

// ---------------- direct-fragment MFMA GEMM, sched_barrier-pinned prefetch ----------------
// Block: 4 waves stacked on rows -> 128 rows x 64 cols; wave tile 32x64 (acc 2x4).
// Chunk = 64 K-cols = 12 x 16B loads. Prefetch chunks 0-2 (36 loads in flight),
// sched_barrier(0) pins them BEFORE the MFMAs -> compiler must emit counted
// vmcnt waits. One latency stall per wave instead of 48.

template<int RELU, int DUAL, int STATS, int SEL3, int K>
__global__ __launch_bounds__(256) void k_gemm_pp(
        const ushort_t* __restrict__ A1, const ushort_t* __restrict__ A2,
        const ushort_t* __restrict__ B1, const ushort_t* __restrict__ B2,
        const float* __restrict__ bias, ushort_t* __restrict__ out,
        int F, float* __restrict__ partials,
        const float* __restrict__ bias2, ushort_t* __restrict__ out2) {
    const int bid = blockIdx.x;
    const int grp = bid >> 3;
    const int y = grp / RQ;
    const int rq = grp - y * RQ;
    const int r = (bid & 7) + (rq << 3);
    if (r >= RC) return;
    const int row0 = r * 128;

    int colblk = y, outsel = 0;
    if (SEL3) { colblk = y & 1; outsel = y >> 1; }
    const int col0 = colblk * 64;
    const ushort_t* __restrict__ Bp = (SEL3 && outsel) ? B2 : B1;
    const float* __restrict__ biasp = (SEL3 && outsel) ? bias2 : bias;
    ushort_t* __restrict__ outp = (SEL3 && outsel) ? out2 : out;

    const int tid = threadIdx.x;
    const int lane = tid & 63;
    const int w = tid >> 6;
    const int q = lane >> 4, lr = lane & 15;
    const int wrow = row0 + w * 32;             // wave's 32-row strip

    size_t aoffr[2];
#pragma unroll
    for (int rf = 0; rf < 2; ++rf) {
        int rr = wrow + rf * 16 + lr;
        if (rr > N_NODES - 1) rr = N_NODES - 1;
        aoffr[rf] = (size_t)rr * K + q * 8;
    }
    size_t boffc[4];
#pragma unroll
    for (int cf = 0; cf < 4; ++cf)
        boffc[cf] = (size_t)(col0 + cf * 16 + lr) * K + q * 8;

    f32x4 acc[2][4];
#pragma unroll
    for (int mf = 0; mf < 2; ++mf)
#pragma unroll
        for (int nf = 0; nf < 4; ++nf)
            acc[mf][nf] = (f32x4){0.f, 0.f, 0.f, 0.f};

    bf16x8 av0[2][2], bv0[2][4], av1[2][2], bv1[2][4];
    bf16x8 av2[2][2], bv2[2][4], av3[2][2], bv3[2][4];

#define LOADCH(AV, BV, CI) do {                                              \
    const ushort_t* MA_ = (DUAL && (CI) >= 2) ? A2 : A1;                     \
    const ushort_t* MB_ = (DUAL && (CI) >= 2) ? B2 : Bp;                     \
    const int kb_ = DUAL ? (((CI) & 1) * 64) : ((CI) * 64);                  \
    _Pragma("unroll")                                                        \
    for (int k0 = 0; k0 < 2; ++k0) {                                         \
        _Pragma("unroll")                                                    \
        for (int rf = 0; rf < 2; ++rf)                                       \
            AV[k0][rf] = *reinterpret_cast<const bf16x8*>(                   \
                MA_ + aoffr[rf] + kb_ + k0 * 32);                            \
        _Pragma("unroll")                                                    \
        for (int cf = 0; cf < 4; ++cf)                                       \
            BV[k0][cf] = *reinterpret_cast<const bf16x8*>(                   \
                MB_ + boffc[cf] + kb_ + k0 * 32);                            \
    } } while (0)

#define MMCH(AV, BV) do {                                                    \
    _Pragma("unroll")                                                        \
    for (int k0 = 0; k0 < 2; ++k0)                                           \
        _Pragma("unroll")                                                    \
        for (int mf = 0; mf < 2; ++mf)                                       \
            _Pragma("unroll")                                                \
            for (int nf = 0; nf < 4; ++nf)                                   \
                acc[mf][nf] = __builtin_amdgcn_mfma_f32_16x16x32_bf16(       \
                    AV[k0][mf], BV[k0][nf], acc[mf][nf], 0, 0, 0);           \
    } while (0)

    // pinned schedule: 3-deep prefetch, then overlap chunk-3 issue with MM0
    LOADCH(av0, bv0, 0);
    LOADCH(av1, bv1, 1);
    LOADCH(av2, bv2, 2);
    __builtin_amdgcn_sched_barrier(0);
    MMCH(av0, bv0);
    __builtin_amdgcn_sched_barrier(0);
    LOADCH(av3, bv3, 3);
    __builtin_amdgcn_sched_barrier(0);
    MMCH(av1, bv1);
    MMCH(av2, bv2);
    MMCH(av3, bv3);

#undef LOADCH
#undef MMCH

    // ---- epilogue: bias/relu/stats in regs, LDS transpose, coalesced 16B stores
    __shared__ __align__(16) short lw[4][32][72];     // 18432 B
    __shared__ float sdf[2][16][64];                  // 8192 B

    float s[4], s2[4];
#pragma unroll
    for (int nf = 0; nf < 4; ++nf) { s[nf] = 0.f; s2[nf] = 0.f; }
#pragma unroll
    for (int nf = 0; nf < 4; ++nf) {
        float bvs = biasp[col0 + nf * 16 + lr];
#pragma unroll
        for (int mf = 0; mf < 2; ++mf) {
#pragma unroll
            for (int b = 0; b < 4; ++b) {
                int rloc = mf * 16 + q * 4 + b;       // row within wave strip
                float v = acc[mf][nf][b] + bvs;
                if (RELU) v = fmaxf(v, 0.f);
                if (STATS && (wrow + rloc) < N_NODES) { s[nf] += v; s2[nf] += v * v; }
                lw[w][rloc][nf * 16 + lr] = (short)f2b(v);
            }
        }
    }
    // same-wave LDS readback (compiler inserts lgkmcnt wait)
#pragma unroll
    for (int it = 0; it < 4; ++it) {
        int row = it * 8 + (lane >> 3);
        int gr = wrow + row;
        if (gr < N_NODES) {
            uint4 vv = *reinterpret_cast<const uint4*>(&lw[w][row][(lane & 7) * 8]);
            *reinterpret_cast<uint4*>(outp + (size_t)gr * F + col0 + (lane & 7) * 8) = vv;
        }
    }

    if constexpr (STATS) {
        const int u = w * 4 + q;                      // 16 contributors per col
#pragma unroll
        for (int nf = 0; nf < 4; ++nf) {
            sdf[0][u][nf * 16 + lr] = s[nf];
            sdf[1][u][nf * 16 + lr] = s2[nf];
        }
        __syncthreads();
        if (tid < 64) {
            float ss = 0.f, qq = 0.f;
#pragma unroll
            for (int u2 = 0; u2 < 16; ++u2) {
                ss += sdf[0][u2][tid];
                qq += sdf[1][u2][tid];
            }
            int cg = col0 + tid;
            partials[(size_t)cg * GXP + r] = ss;
            partials[(size_t)(F + cg) * GXP + r] = qq;
        }
    }
}

// ---------------- BN: reduce partials -> scale/shift ----------------

template<int F>
__global__ __launch_bounds__(64) void k_bn_scsh(
        const float* __restrict__ partials, const float* __restrict__ gamma,
        const float* __restrict__ beta, float* __restrict__ scsh) {
    const int c = blockIdx.x;
    const int l = threadIdx.x;
    float s = 0.f, q2 = 0.f;
    for (int g = l; g < RC; g += 64) {
        s += partials[(size_t)c * GXP + g];
        q2 += partials[(size_t)(F + c) * GXP + g];
    }
#pragma unroll
    for (int off = 1; off < 64; off <<= 1) {
        s += __shfl_xor(s, off);
        q2 += __shfl_xor(q2, off);
    }
    if (l == 0) {
        float mean = s * (1.0f / N_NODES);
        float var = q2 * (1.0f / N_NODES) - mean * mean;
        float sc = gamma[c] * rsqrtf(var + BN_EPS_F);
        scsh[c] = sc;
        scsh[F + c] = beta[c] - mean * sc;
    }
}

// ---------------- launch ----------------

extern "C" void kernel_launch(void* const* d_in, const int* in_sizes, int n_in,
                              void* d_out, int out_size, void* d_ws, size_t ws_size,
                              hipStream_t stream) {
    (void)in_sizes; (void)n_in; (void)out_size; (void)ws_size;
    const float* x   = (const float*)d_in[0];
    const int*   src = (const int*)d_in[1];
    const int*   dst = (const int*)d_in[2];
    const float* eps = (const float*)d_in[3];
    const float* W1l = (const float*)d_in[4];
    const float* W1r = (const float*)d_in[5];
    const float* b1  = (const float*)d_in[6];
    const float* g1  = (const float*)d_in[7];
    const float* be1 = (const float*)d_in[8];
    const float* W2l = (const float*)d_in[9];
    const float* W2r = (const float*)d_in[10];
    const float* b2  = (const float*)d_in[11];
    const float* g2  = (const float*)d_in[12];
    const float* be2 = (const float*)d_in[13];
    const float* W3l = (const float*)d_in[14];
    const float* W3r = (const float*)d_in[15];
    const float* b3  = (const float*)d_in[16];
    float* z = (float*)d_out;

    char* ws = (char*)d_ws;
    size_t off = 0;
    auto alloc = [&](size_t bytes) -> char* {
        char* p = ws + off;
        off += (bytes + 255) & ~(size_t)255;
        return p;
    };
    int*      deg2   = (int*)alloc((size_t)N_NODES * 16 * 4);   // padded: 1 counter / 64B line; zeroed
    size_t zero_bytes = off;
    ushort_t* rank   = (ushort_t*)alloc((size_t)N_EDGES * 2);
    ushort_t* eids   = (ushort_t*)alloc((size_t)N_EDGES * 2);
    float*    scshs  = (float*)alloc(1024 * 4);         // scsh1 (256) + scsh2 (512)
    float*    biases = (float*)alloc(512 * 4);          // bias2 + bias3l + bias3r
    int*      offs   = (int*)alloc(N_NODES * 4);
    int*      bsum   = (int*)alloc(128 * 4);
    int*      degc   = (int*)alloc(N_NODES * 4);
    float*    invd   = (float*)alloc(N_NODES * 4);
    ushort_t* xb     = (ushort_t*)alloc((size_t)N_NODES * 128 * 2);
    ushort_t* h1b    = (ushort_t*)alloc((size_t)N_NODES * 128 * 2);
    ushort_t* h2b    = (ushort_t*)alloc((size_t)N_NODES * 256 * 2);
    ushort_t* aggrb  = (ushort_t*)alloc((size_t)N_NODES * 256 * 2);   // layer-1/2 aggr; reused as t3
    ushort_t* u3b    = (ushort_t*)alloc((size_t)N_NODES * 128 * 2);
    float*    parts  = (float*)alloc((size_t)512 * GXP * 4);          // [2F][GXP], F<=256
    ushort_t* wt1l   = (ushort_t*)alloc(128 * 128 * 2);
    ushort_t* wt1r   = (ushort_t*)alloc(128 * 128 * 2);
    ushort_t* wt2l   = (ushort_t*)alloc(256 * 128 * 2);
    ushort_t* wt2r   = (ushort_t*)alloc(256 * 128 * 2);
    ushort_t* wt3l   = (ushort_t*)alloc(128 * 256 * 2);
    ushort_t* wt3r   = (ushort_t*)alloc(128 * 256 * 2);
    ushort_t* t3b    = aggrb;   // layer-3: t3 (bf16 [N,128]); aggrb free by then

    float* scsh1  = scshs;            // [sc1(128) | sh1(128)]
    float* scsh2  = scshs + 256;      // [sc2(256) | sh2(256)]
    float* bias2  = biases;           // 256
    float* bias3l = biases + 256;     // 128
    float* bias3r = biases + 384;     // 128

    // CSR build: zero deg2 (3.2MB), then ONE fused dispatch (atomics || x->bf16 || W transposes)
    k_zero_i32<<<((int)(zero_bytes / 4) + 255) / 256, 256, 0, stream>>>((int*)ws, (int)(zero_bytes / 4));
    k_pre<<<6506, 256, 0, stream>>>(dst, deg2, rank, x, xb, W1l, W1r, W2l, wt1l, wt1r, wt2l);
    k_scan1<<<SCAN_NB, SCAN_BS, 0, stream>>>(deg2, offs, bsum);
    k_scan2<<<1, 128, 0, stream>>>(bsum, SCAN_NB);
    k_scan3<<<(N_NODES + 255) / 256, 256, 0, stream>>>(deg2, offs, bsum, invd, degc);
    k_fill2<<<(N_EDGES + 255) / 256, 256, 0, stream>>>(src, dst, offs, rank, eids);

    const int AGG_BLKS = N_NODES / 16;        // 3125: one 16-lane group per node
    const int GEMM_G = 8 * RQ;                // 392 blocks per (colblk,outsel) variant

    // ---- Layer 1: SAGE(x) -> relu (+fused BN stats)  (K=128, 2 colblocks)
    k_agg16<0><<<AGG_BLKS, 256, 0, stream>>>(xb, eids, offs, degc, invd, nullptr, aggrb);
    k_gemm_pp<1, 1, 1, 0, 128><<<GEMM_G * 2, 256, 0, stream>>>(
        aggrb, xb, wt1l, wt1r, b1, h1b, 128, parts, nullptr, nullptr);
    k_bn_scsh<128><<<128, 64, 0, stream>>>(parts, g1, be1, scsh1);

    // ---- Layer 2: BN1 absorbed (agg-side fused, self-side in wt2r/bias2)  (K=128, 4 colblocks)
    k_prep2<<<129, 256, 0, stream>>>(W2r, b2, scsh1, wt2r, bias2);
    k_agg16<1><<<AGG_BLKS, 256, 0, stream>>>(h1b, eids, offs, degc, invd, scsh1, aggrb);
    k_gemm_pp<1, 1, 1, 0, 128><<<GEMM_G * 4, 256, 0, stream>>>(
        aggrb, h1b, wt2l, wt2r, bias2, h2b, 256, parts, nullptr, nullptr);
    k_bn_scsh<256><<<256, 64, 0, stream>>>(parts, g2, be2, scsh2);

    // ---- Layer 3 (commuted, BN2 absorbed): ONE dispatch, SEL3 picks output
    //      outsel=0: t3 = h2@wt3l' + bias3l; outsel=1: u3 = h2@wt3r' + bias3r
    k_prep3<<<257, 256, 0, stream>>>(W3l, W3r, b3, scsh2, wt3l, wt3r, bias3l, bias3r);
    k_gemm_pp<0, 0, 0, 1, 256><<<GEMM_G * 4, 256, 0, stream>>>(
        h2b, nullptr, wt3l, wt3r, bias3l, t3b, 128, nullptr, bias3r, u3b);
    k_agg_reparam<<<AGG_BLKS, 256, 0, stream>>>(t3b, eids, offs, degc, invd, u3b, eps, z);
}

// Round 15
// 238.849 us; speedup vs baseline: 1.3410x; 1.1502x over previous
//
#include <hip/hip_runtime.h>
#include <math.h>

#define N_NODES 50000
#define N_EDGES 800000
#define BN_EPS_F 1e-5f
#define SCAN_BS 512
#define SCAN_NB 98   // ceil(50000/512)
#define RC 391       // row-chunks of 128 rows
#define RQ 49        // ceil(RC/8)
#define GXP 392      // padded partials stride (>= RC)

typedef unsigned short ushort_t;
typedef unsigned int uint_t;
typedef __attribute__((ext_vector_type(8))) short bf16x8;
typedef __attribute__((ext_vector_type(4))) float f32x4;

static __device__ __forceinline__ float4 ld4(const float* p) {
    return *reinterpret_cast<const float4*>(p);
}
static __device__ __forceinline__ float bf2f(ushort_t u) {
    return __uint_as_float(((uint_t)u) << 16);
}
static __device__ __forceinline__ ushort_t f2b(float f) {
    uint_t u = __float_as_uint(f);
    u += 0x7fffu + ((u >> 16) & 1u);
    return (ushort_t)(u >> 16);
}
static __device__ __forceinline__ void gload16(const void* g, void* l) {
    __builtin_amdgcn_global_load_lds(
        (const __attribute__((address_space(1))) void*)g,
        (__attribute__((address_space(3))) void*)l, 16, 0, 0);
}

// ---------------- CSR build ----------------

__global__ void k_zero_i32(int* __restrict__ p, int n) {
    int i = blockIdx.x * blockDim.x + threadIdx.x;
    if (i < n) p[i] = 0;
}

// fused: countrank (even blocks; deg2 padded 1 counter/64B line) + x->bf16 (odd) + W transposes (tail)
__global__ void k_pre(const int* __restrict__ dst, int* __restrict__ deg2,
                      ushort_t* __restrict__ rank,
                      const float* __restrict__ x, ushort_t* __restrict__ xb,
                      const float* __restrict__ W1l, const float* __restrict__ W1r,
                      const float* __restrict__ W2l, ushort_t* __restrict__ wt1l,
                      ushort_t* __restrict__ wt1r, ushort_t* __restrict__ wt2l) {
    int b = blockIdx.x;
    if (b < 6250) {
        int role = b & 1;
        int id = (b >> 1) * 256 + threadIdx.x;   // < 800000 exact
        if (role == 0) {
            rank[id] = (ushort_t)atomicAdd(&deg2[dst[id] * 16], 1);
        } else {
            float4 a = ld4(x + (size_t)id * 8);
            float4 c = ld4(x + (size_t)id * 8 + 4);
            uint_t o0 = (uint_t)f2b(a.x) | ((uint_t)f2b(a.y) << 16);
            uint_t o1 = (uint_t)f2b(a.z) | ((uint_t)f2b(a.w) << 16);
            uint_t o2 = (uint_t)f2b(c.x) | ((uint_t)f2b(c.y) << 16);
            uint_t o3 = (uint_t)f2b(c.z) | ((uint_t)f2b(c.w) << 16);
            *reinterpret_cast<uint4*>(xb + (size_t)id * 8) = make_uint4(o0, o1, o2, o3);
        }
    } else {
        int idx = (b - 6250) * 256 + threadIdx.x;   // 0..65535
        if (idx < 16384) {
            int f = idx >> 7, k = idx & 127;
            wt1l[idx] = f2b(W1l[(size_t)k * 128 + f]);
        } else if (idx < 32768) {
            int j = idx - 16384;
            int f = j >> 7, k = j & 127;
            wt1r[j] = f2b(W1r[(size_t)k * 128 + f]);
        } else {
            int j = idx - 32768;                    // F=256 K=128
            int f = j >> 7, k = j & 127;
            wt2l[j] = f2b(W2l[(size_t)k * 256 + f]);
        }
    }
}

__global__ void k_scan1(const int* __restrict__ deg2, int* __restrict__ offs, int* __restrict__ bsum) {
    __shared__ int sh[SCAN_BS];
    int t = threadIdx.x;
    int g = blockIdx.x * SCAN_BS + t;
    int v = (g < N_NODES) ? deg2[g * 16] : 0;
    sh[t] = v;
    __syncthreads();
    for (int off = 1; off < SCAN_BS; off <<= 1) {
        int add = (t >= off) ? sh[t - off] : 0;
        __syncthreads();
        sh[t] += add;
        __syncthreads();
    }
    if (g < N_NODES) offs[g] = sh[t] - v;
    if (t == SCAN_BS - 1) bsum[blockIdx.x] = sh[t];
}

__global__ void k_scan2(int* __restrict__ bsum, int nb) {
    __shared__ int sh[128];
    int t = threadIdx.x;
    int v = (t < nb) ? bsum[t] : 0;
    sh[t] = v;
    __syncthreads();
    for (int off = 1; off < 128; off <<= 1) {
        int add = (t >= off) ? sh[t - off] : 0;
        __syncthreads();
        sh[t] += add;
        __syncthreads();
    }
    if (t < nb) bsum[t] = sh[t] - v;
}

__global__ void k_scan3(const int* __restrict__ deg2, int* __restrict__ offs,
                        const int* __restrict__ bsum, float* __restrict__ inv_deg,
                        int* __restrict__ degc) {
    int g = blockIdx.x * blockDim.x + threadIdx.x;
    if (g < N_NODES) {
        offs[g] += bsum[g / SCAN_BS];
        int d = deg2[g * 16];
        degc[g] = d;
        inv_deg[g] = 1.0f / (float)(d > 1 ? d : 1);
    }
}

// atomic-free scatter, ushort payload
__global__ void k_fill2(const int* __restrict__ src, const int* __restrict__ dst,
                        const int* __restrict__ offs, const ushort_t* __restrict__ rank,
                        ushort_t* __restrict__ eids) {
    int e = blockIdx.x * blockDim.x + threadIdx.x;
    if (e < N_EDGES) eids[offs[dst[e]] + (int)rank[e]] = (ushort_t)src[e];
}

// ---------------- late weight prep (need BN scsh) ----------------

__global__ void k_prep2(const float* __restrict__ W2r, const float* __restrict__ b2,
                        const float* __restrict__ scsh1, ushort_t* __restrict__ wt2r,
                        float* __restrict__ bias2) {
    int bid = blockIdx.x;
    if (bid < 128) {
        int idx = bid * 256 + threadIdx.x;      // F=256 K=128
        int f = idx >> 7, k = idx & 127;
        wt2r[idx] = f2b(scsh1[k] * W2r[(size_t)k * 256 + f]);
    } else {
        int f = threadIdx.x;
        float s = b2[f];
        for (int k = 0; k < 128; ++k) s += scsh1[128 + k] * W2r[(size_t)k * 256 + f];
        bias2[f] = s;
    }
}

__global__ void k_prep3(const float* __restrict__ W3l, const float* __restrict__ W3r,
                        const float* __restrict__ b3, const float* __restrict__ scsh2,
                        ushort_t* __restrict__ wt3l, ushort_t* __restrict__ wt3r,
                        float* __restrict__ bias3l, float* __restrict__ bias3r) {
    int bid = blockIdx.x;
    if (bid < 256) {
        int half = bid >> 7;
        int idx = (bid & 127) * 256 + threadIdx.x;   // F=128 K=256
        int f = idx >> 8, k = idx & 255;
        const float* W = half ? W3r : W3l;
        ushort_t* WT = half ? wt3r : wt3l;
        WT[idx] = f2b(scsh2[k] * W[(size_t)k * 128 + f]);
    } else {
        int t = threadIdx.x;
        int f = t & 127;
        const float* W = (t < 128) ? W3l : W3r;
        float s = (t < 128) ? 0.f : b3[f];
        for (int k = 0; k < 256; ++k) s += scsh2[256 + k] * W[(size_t)k * 128 + f];
        float* out = (t < 128) ? bias3l : bias3r;
        out[f] = s;
    }
}

// ---------------- gather core: one 16-lane GROUP per node, 8-deep pipeline ----------------

#define ACCUM8(a) do { \
    acc[0] += bf2f((ushort_t)(a).x); acc[1] += bf2f((ushort_t)((a).x >> 16)); \
    acc[2] += bf2f((ushort_t)(a).y); acc[3] += bf2f((ushort_t)((a).y >> 16)); \
    acc[4] += bf2f((ushort_t)(a).z); acc[5] += bf2f((ushort_t)((a).z >> 16)); \
    acc[6] += bf2f((ushort_t)(a).w); acc[7] += bf2f((ushort_t)((a).w >> 16)); } while (0)

static __device__ __forceinline__ void gather_rows_g(
        const ushort_t* __restrict__ h, const ushort_t* __restrict__ eids,
        int beg, int d, size_t coff, float* acc) {
    int j = 0;
    for (; j + 8 <= d; j += 8) {
        uint4 a[8];
#pragma unroll
        for (int k = 0; k < 8; ++k) {
            int s = eids[beg + j + k];
            a[k] = *reinterpret_cast<const uint4*>(h + (size_t)s * 128 + coff);
        }
#pragma unroll
        for (int k = 0; k < 8; ++k) ACCUM8(a[k]);
    }
    for (; j + 4 <= d; j += 4) {
        uint4 a[4];
#pragma unroll
        for (int k = 0; k < 4; ++k) {
            int s = eids[beg + j + k];
            a[k] = *reinterpret_cast<const uint4*>(h + (size_t)s * 128 + coff);
        }
#pragma unroll
        for (int k = 0; k < 4; ++k) ACCUM8(a[k]);
    }
    for (; j + 2 <= d; j += 2) {
        int s0 = eids[beg + j];
        int s1 = eids[beg + j + 1];
        uint4 a = *reinterpret_cast<const uint4*>(h + (size_t)s0 * 128 + coff);
        uint4 b = *reinterpret_cast<const uint4*>(h + (size_t)s1 * 128 + coff);
        ACCUM8(a); ACCUM8(b);
    }
    if (j < d) {
        int s0 = eids[beg + j];
        uint4 a = *reinterpret_cast<const uint4*>(h + (size_t)s0 * 128 + coff);
        ACCUM8(a);
    }
}

template<int BN>
__global__ __launch_bounds__(256) void k_agg16(
        const ushort_t* __restrict__ h, const ushort_t* __restrict__ eids,
        const int* __restrict__ offs, const int* __restrict__ deg,
        const float* __restrict__ inv_deg, const float* __restrict__ scsh,
        ushort_t* __restrict__ out) {
    const int node = blockIdx.x * 16 + (threadIdx.x >> 4);
    const int lr = threadIdx.x & 15;
    if (node >= N_NODES) return;
    float acc[8];
#pragma unroll
    for (int v = 0; v < 8; ++v) acc[v] = 0.f;
    const int beg = offs[node];
    const int d = deg[node];
    const size_t coff = (size_t)lr * 8;
    gather_rows_g(h, eids, beg, d, coff, acc);

    float sc = inv_deg[node];
    if (BN) {
        float4 sa0 = ld4(&scsh[lr * 8]), sa1 = ld4(&scsh[lr * 8 + 4]);
        float4 sb0 = ld4(&scsh[128 + lr * 8]), sb1 = ld4(&scsh[128 + lr * 8 + 4]);
        if (d > 0) {
            acc[0] = acc[0] * sc * sa0.x + sb0.x; acc[1] = acc[1] * sc * sa0.y + sb0.y;
            acc[2] = acc[2] * sc * sa0.z + sb0.z; acc[3] = acc[3] * sc * sa0.w + sb0.w;
            acc[4] = acc[4] * sc * sa1.x + sb1.x; acc[5] = acc[5] * sc * sa1.y + sb1.y;
            acc[6] = acc[6] * sc * sa1.z + sb1.z; acc[7] = acc[7] * sc * sa1.w + sb1.w;
        } else {
#pragma unroll
            for (int v = 0; v < 8; ++v) acc[v] = 0.f;
        }
    } else {
#pragma unroll
        for (int v = 0; v < 8; ++v) acc[v] *= sc;
    }
    uint4 o;
    o.x = (uint_t)f2b(acc[0]) | ((uint_t)f2b(acc[1]) << 16);
    o.y = (uint_t)f2b(acc[2]) | ((uint_t)f2b(acc[3]) << 16);
    o.z = (uint_t)f2b(acc[4]) | ((uint_t)f2b(acc[5]) << 16);
    o.w = (uint_t)f2b(acc[6]) | ((uint_t)f2b(acc[7]) << 16);
    *reinterpret_cast<uint4*>(out + (size_t)node * 128 + coff) = o;
}

__global__ __launch_bounds__(256) void k_agg_reparam(
        const ushort_t* __restrict__ t3, const ushort_t* __restrict__ eids,
        const int* __restrict__ offs, const int* __restrict__ deg,
        const float* __restrict__ inv_deg, const ushort_t* __restrict__ u,
        const float* __restrict__ eps, float* __restrict__ z) {
    const int node = blockIdx.x * 16 + (threadIdx.x >> 4);
    const int lr = threadIdx.x & 15;
    if (node >= N_NODES) return;
    float acc[8];
#pragma unroll
    for (int v = 0; v < 8; ++v) acc[v] = 0.f;
    const int beg = offs[node];
    const int d = deg[node];
    const size_t coff = (size_t)lr * 8;
    gather_rows_g(t3, eids, beg, d, coff, acc);
    float ls[8];
#pragma unroll
    for (int v = 0; v < 8; ++v) ls[v] = __shfl_down(acc[v], 8);

    if (lr < 8) {
        float sc = inv_deg[node];
        uint4 um4 = *reinterpret_cast<const uint4*>(u + (size_t)node * 128 + lr * 8);
        uint4 ul4 = *reinterpret_cast<const uint4*>(u + (size_t)node * 128 + 64 + lr * 8);
        const float* ep = eps + (size_t)node * 64 + lr * 8;
        float4 e0 = ld4(ep), e1 = ld4(ep + 4);
        float um[8], ul[8];
        um[0] = bf2f((ushort_t)um4.x); um[1] = bf2f((ushort_t)(um4.x >> 16));
        um[2] = bf2f((ushort_t)um4.y); um[3] = bf2f((ushort_t)(um4.y >> 16));
        um[4] = bf2f((ushort_t)um4.z); um[5] = bf2f((ushort_t)(um4.z >> 16));
        um[6] = bf2f((ushort_t)um4.w); um[7] = bf2f((ushort_t)(um4.w >> 16));
        ul[0] = bf2f((ushort_t)ul4.x); ul[1] = bf2f((ushort_t)(ul4.x >> 16));
        ul[2] = bf2f((ushort_t)ul4.y); ul[3] = bf2f((ushort_t)(ul4.y >> 16));
        ul[4] = bf2f((ushort_t)ul4.z); ul[5] = bf2f((ushort_t)(ul4.z >> 16));
        ul[6] = bf2f((ushort_t)ul4.w); ul[7] = bf2f((ushort_t)(ul4.w >> 16));
        float4 o0, o1;
        o0.x = (acc[0] * sc + um[0]) + expf(ls[0] * sc + ul[0]) * e0.x;
        o0.y = (acc[1] * sc + um[1]) + expf(ls[1] * sc + ul[1]) * e0.y;
        o0.z = (acc[2] * sc + um[2]) + expf(ls[2] * sc + ul[2]) * e0.z;
        o0.w = (acc[3] * sc + um[3]) + expf(ls[3] * sc + ul[3]) * e0.w;
        o1.x = (acc[4] * sc + um[4]) + expf(ls[4] * sc + ul[4]) * e1.x;
        o1.y = (acc[5] * sc + um[5]) + expf(ls[5] * sc + ul[5]) * e1.y;
        o1.z = (acc[6] * sc + um[6]) + expf(ls[6] * sc + ul[6]) * e1.z;
        o1.w = (acc[7] * sc + um[7]) + expf(ls[7] * sc + ul[7]) * e1.w;
        float* zp = z + (size_t)node * 64 + lr * 8;
        *reinterpret_cast<float4*>(zp) = o0;
        *reinterpret_cast<float4*>(zp + 4) = o1;
    }
}

// ---------------- MFMA GEMM: global_load_lds + double-buffer (T3 minimum 2-phase) ----------------
// 128x128 tile, BK=32, 4 waves (each 64x64). Per K-step: STAGE(next buf) ||
// ds_read+MFMA(cur buf); ONE __syncthreads per step (its vmcnt(0) drain is
// exactly the wanted "staged loads landed" condition; stage latency hides
// under the MFMA block). LDS 2x16KB; 16B-slot XOR swizzle (verified R2-R8).
// XCD-class decode: class = bid&7 -> row-chunk locality per L2.
// SEL3: y selects {B,bias,out} pair (layer-3 dual output, col0=0).

template<int RELU, int DUAL, int STATS, int SEL3, int K>
__global__ __launch_bounds__(256) void k_gemm_db(
        const ushort_t* __restrict__ A1, const ushort_t* __restrict__ A2,
        const ushort_t* __restrict__ B1, const ushort_t* __restrict__ B2,
        const float* __restrict__ bias, ushort_t* __restrict__ out,
        int F, float* __restrict__ partials,
        const float* __restrict__ bias2, ushort_t* __restrict__ out2) {
    __shared__ __align__(16) short lds[2][8192];   // per buf: A [0,4096), B [4096,8192)
    const int bid = blockIdx.x;
    const int grp = bid >> 3;
    const int y = grp / RQ;
    const int rq = grp - y * RQ;
    const int r = (bid & 7) + (rq << 3);
    if (r >= RC) return;
    const int row0 = r * 128;

    int colblk = y, outsel = 0;
    if (SEL3) { colblk = 0; outsel = y; }
    const int col0 = colblk * 128;
    const ushort_t* __restrict__ Bp = (SEL3 && outsel) ? B2 : B1;
    const float* __restrict__ biasp = (SEL3 && outsel) ? bias2 : bias;
    ushort_t* __restrict__ outp = (SEL3 && outsel) ? out2 : out;

    const int tid = threadIdx.x;
    const int lane = tid & 63;
    const int w = tid >> 6;
    const int wr = (w >> 1) * 64;
    const int wc = (w & 1) * 64;

    // staging map (verified R2-R8): chunk c=(p*4+w)*64+lane -> row r_=c>>2,
    // slot sp=c&3; LDS linear, SOURCE pre-swizzled with sp ^ ((r_>>1)&3)
    int rowA[2], slA[2];
#pragma unroll
    for (int p = 0; p < 2; ++p) {
        int c = (p * 4 + w) * 64 + lane;
        int r_ = c >> 2, sp = c & 3;
        rowA[p] = r_;
        slA[p] = sp ^ ((r_ >> 1) & 3);
    }
    const int q = lane >> 4, lr = lane & 15;
    int aoff[4], boff[4];
#pragma unroll
    for (int f = 0; f < 4; ++f) {
        int ra = wr + f * 16 + lr;
        aoff[f] = ra * 32 + (q ^ ((ra >> 1) & 3)) * 8;
        int rb = wc + f * 16 + lr;
        boff[f] = 4096 + rb * 32 + (q ^ ((rb >> 1) & 3)) * 8;
    }

    f32x4 acc[4][4];
#pragma unroll
    for (int mf = 0; mf < 4; ++mf)
#pragma unroll
        for (int nf = 0; nf < 4; ++nf)
            acc[mf][nf] = (f32x4){0.f, 0.f, 0.f, 0.f};

    auto stage = [&](int buf, int t) {
        const ushort_t* A = A1;
        const ushort_t* B = SEL3 ? Bp : B1;
        int k0;
        if (DUAL) {
            if (t >= 4) { A = A2; B = B2; }
            k0 = (t & 3) * 32;
        } else {
            k0 = t * 32;
        }
        short* base = &lds[buf][0];
#pragma unroll
        for (int p = 0; p < 2; ++p) {
            int gr = row0 + rowA[p];
            if (gr > N_NODES - 1) gr = N_NODES - 1;
            gload16(A + (size_t)gr * K + k0 + slA[p] * 8, base + (p * 4 + w) * 512);
            int gc = col0 + rowA[p];
            gload16(B + (size_t)gc * K + k0 + slA[p] * 8, base + 4096 + (p * 4 + w) * 512);
        }
    };

    constexpr int NT = DUAL ? 8 : (K / 32);
    stage(0, 0);
    __syncthreads();
    int cur = 0;
    for (int t = 0; t < NT; ++t) {
        if (t + 1 < NT) stage(cur ^ 1, t + 1);   // issue next-tile loads first
        bf16x8 av[4], bv[4];
#pragma unroll
        for (int f = 0; f < 4; ++f) {
            av[f] = *reinterpret_cast<const bf16x8*>(&lds[cur][aoff[f]]);
            bv[f] = *reinterpret_cast<const bf16x8*>(&lds[cur][boff[f]]);
        }
#pragma unroll
        for (int mf = 0; mf < 4; ++mf)
#pragma unroll
            for (int nf = 0; nf < 4; ++nf)
                acc[mf][nf] = __builtin_amdgcn_mfma_f32_16x16x32_bf16(
                    av[mf], bv[nf], acc[mf][nf], 0, 0, 0);
        __syncthreads();   // drains vmcnt(0): next tile landed; reads of cur done
        cur ^= 1;
    }

    // epilogue: D lane map (m89): col = lane&15, row = (lane>>4)*4 + b
    const int orow = row0 + wr + q * 4;
    const int ocol = col0 + wc + lr;
    float s[4], s2[4];
#pragma unroll
    for (int nf = 0; nf < 4; ++nf) { s[nf] = 0.f; s2[nf] = 0.f; }
#pragma unroll
    for (int nf = 0; nf < 4; ++nf) {
        int colg = ocol + nf * 16;
        float bvs = biasp[colg];
#pragma unroll
        for (int mf = 0; mf < 4; ++mf) {
#pragma unroll
            for (int b = 0; b < 4; ++b) {
                int rr = orow + mf * 16 + b;
                if (rr < N_NODES) {
                    float v = acc[mf][nf][b] + bvs;
                    if (RELU) v = fmaxf(v, 0.f);
                    if (STATS) { s[nf] += v; s2[nf] += v * v; }
                    outp[(size_t)rr * F + colg] = f2b(v);
                }
            }
        }
    }

    if constexpr (STATS) {
        __syncthreads();                          // staging LDS now dead; reuse
        float* sdf = (float*)&lds[0][0];          // 2048 floats = 8KB
        const int u = (w >> 1) * 4 + q;           // 8 contributors per column
#pragma unroll
        for (int nf = 0; nf < 4; ++nf) {
            int cb = wc + nf * 16 + lr;           // 0..127 within block
            sdf[u * 128 + cb] = s[nf];
            sdf[1024 + u * 128 + cb] = s2[nf];
        }
        __syncthreads();
        if (tid < 128) {
            float ss = 0.f, qq = 0.f;
#pragma unroll
            for (int u2 = 0; u2 < 8; ++u2) {
                ss += sdf[u2 * 128 + tid];
                qq += sdf[1024 + u2 * 128 + tid];
            }
            int cg = col0 + tid;
            partials[(size_t)cg * GXP + r] = ss;
            partials[(size_t)(F + cg) * GXP + r] = qq;
        }
    }
}

// ---------------- BN: reduce partials -> scale/shift ----------------

template<int F>
__global__ __launch_bounds__(64) void k_bn_scsh(
        const float* __restrict__ partials, const float* __restrict__ gamma,
        const float* __restrict__ beta, float* __restrict__ scsh) {
    const int c = blockIdx.x;
    const int l = threadIdx.x;
    float s = 0.f, q2 = 0.f;
    for (int g = l; g < RC; g += 64) {
        s += partials[(size_t)c * GXP + g];
        q2 += partials[(size_t)(F + c) * GXP + g];
    }
#pragma unroll
    for (int off = 1; off < 64; off <<= 1) {
        s += __shfl_xor(s, off);
        q2 += __shfl_xor(q2, off);
    }
    if (l == 0) {
        float mean = s * (1.0f / N_NODES);
        float var = q2 * (1.0f / N_NODES) - mean * mean;
        float sc = gamma[c] * rsqrtf(var + BN_EPS_F);
        scsh[c] = sc;
        scsh[F + c] = beta[c] - mean * sc;
    }
}

// ---------------- launch ----------------

extern "C" void kernel_launch(void* const* d_in, const int* in_sizes, int n_in,
                              void* d_out, int out_size, void* d_ws, size_t ws_size,
                              hipStream_t stream) {
    (void)in_sizes; (void)n_in; (void)out_size; (void)ws_size;
    const float* x   = (const float*)d_in[0];
    const int*   src = (const int*)d_in[1];
    const int*   dst = (const int*)d_in[2];
    const float* eps = (const float*)d_in[3];
    const float* W1l = (const float*)d_in[4];
    const float* W1r = (const float*)d_in[5];
    const float* b1  = (const float*)d_in[6];
    const float* g1  = (const float*)d_in[7];
    const float* be1 = (const float*)d_in[8];
    const float* W2l = (const float*)d_in[9];
    const float* W2r = (const float*)d_in[10];
    const float* b2  = (const float*)d_in[11];
    const float* g2  = (const float*)d_in[12];
    const float* be2 = (const float*)d_in[13];
    const float* W3l = (const float*)d_in[14];
    const float* W3r = (const float*)d_in[15];
    const float* b3  = (const float*)d_in[16];
    float* z = (float*)d_out;

    char* ws = (char*)d_ws;
    size_t off = 0;
    auto alloc = [&](size_t bytes) -> char* {
        char* p = ws + off;
        off += (bytes + 255) & ~(size_t)255;
        return p;
    };
    int*      deg2   = (int*)alloc((size_t)N_NODES * 16 * 4);   // padded: 1 counter / 64B line; zeroed
    size_t zero_bytes = off;
    ushort_t* rank   = (ushort_t*)alloc((size_t)N_EDGES * 2);
    ushort_t* eids   = (ushort_t*)alloc((size_t)N_EDGES * 2);
    float*    scshs  = (float*)alloc(1024 * 4);         // scsh1 (256) + scsh2 (512)
    float*    biases = (float*)alloc(512 * 4);          // bias2 + bias3l + bias3r
    int*      offs   = (int*)alloc(N_NODES * 4);
    int*      bsum   = (int*)alloc(128 * 4);
    int*      degc   = (int*)alloc(N_NODES * 4);
    float*    invd   = (float*)alloc(N_NODES * 4);
    ushort_t* xb     = (ushort_t*)alloc((size_t)N_NODES * 128 * 2);
    ushort_t* h1b    = (ushort_t*)alloc((size_t)N_NODES * 128 * 2);
    ushort_t* h2b    = (ushort_t*)alloc((size_t)N_NODES * 256 * 2);
    ushort_t* aggrb  = (ushort_t*)alloc((size_t)N_NODES * 256 * 2);   // layer-1/2 aggr; reused as t3
    ushort_t* u3b    = (ushort_t*)alloc((size_t)N_NODES * 128 * 2);
    float*    parts  = (float*)alloc((size_t)512 * GXP * 4);          // [2F][GXP], F<=256
    ushort_t* wt1l   = (ushort_t*)alloc(128 * 128 * 2);
    ushort_t* wt1r   = (ushort_t*)alloc(128 * 128 * 2);
    ushort_t* wt2l   = (ushort_t*)alloc(256 * 128 * 2);
    ushort_t* wt2r   = (ushort_t*)alloc(256 * 128 * 2);
    ushort_t* wt3l   = (ushort_t*)alloc(128 * 256 * 2);
    ushort_t* wt3r   = (ushort_t*)alloc(128 * 256 * 2);
    ushort_t* t3b    = aggrb;   // layer-3: t3 (bf16 [N,128]); aggrb free by then

    float* scsh1  = scshs;            // [sc1(128) | sh1(128)]
    float* scsh2  = scshs + 256;      // [sc2(256) | sh2(256)]
    float* bias2  = biases;           // 256
    float* bias3l = biases + 256;     // 128
    float* bias3r = biases + 384;     // 128

    // CSR build: zero deg2 (3.2MB), then ONE fused dispatch (atomics || x->bf16 || W transposes)
    k_zero_i32<<<((int)(zero_bytes / 4) + 255) / 256, 256, 0, stream>>>((int*)ws, (int)(zero_bytes / 4));
    k_pre<<<6506, 256, 0, stream>>>(dst, deg2, rank, x, xb, W1l, W1r, W2l, wt1l, wt1r, wt2l);
    k_scan1<<<SCAN_NB, SCAN_BS, 0, stream>>>(deg2, offs, bsum);
    k_scan2<<<1, 128, 0, stream>>>(bsum, SCAN_NB);
    k_scan3<<<(N_NODES + 255) / 256, 256, 0, stream>>>(deg2, offs, bsum, invd, degc);
    k_fill2<<<(N_EDGES + 255) / 256, 256, 0, stream>>>(src, dst, offs, rank, eids);

    const int AGG_BLKS = N_NODES / 16;        // 3125: one 16-lane group per node
    const int GEMM_G = 8 * RQ;                // 392 blocks per (colblk,outsel) variant

    // ---- Layer 1: SAGE(x) -> relu (+fused BN stats)  (K=128, F=128: 1 col-block)
    k_agg16<0><<<AGG_BLKS, 256, 0, stream>>>(xb, eids, offs, degc, invd, nullptr, aggrb);
    k_gemm_db<1, 1, 1, 0, 128><<<GEMM_G, 256, 0, stream>>>(
        aggrb, xb, wt1l, wt1r, b1, h1b, 128, parts, nullptr, nullptr);
    k_bn_scsh<128><<<128, 64, 0, stream>>>(parts, g1, be1, scsh1);

    // ---- Layer 2: BN1 absorbed (agg-side fused, self-side in wt2r/bias2)  (K=128, F=256: 2 col-blocks)
    k_prep2<<<129, 256, 0, stream>>>(W2r, b2, scsh1, wt2r, bias2);
    k_agg16<1><<<AGG_BLKS, 256, 0, stream>>>(h1b, eids, offs, degc, invd, scsh1, aggrb);
    k_gemm_db<1, 1, 1, 0, 128><<<GEMM_G * 2, 256, 0, stream>>>(
        aggrb, h1b, wt2l, wt2r, bias2, h2b, 256, parts, nullptr, nullptr);
    k_bn_scsh<256><<<256, 64, 0, stream>>>(parts, g2, be2, scsh2);

    // ---- Layer 3 (commuted, BN2 absorbed): ONE dispatch, SEL3 picks output
    //      y=0: t3 = h2@wt3l' + bias3l; y=1: u3 = h2@wt3r' + bias3r
    k_prep3<<<257, 256, 0, stream>>>(W3l, W3r, b3, scsh2, wt3l, wt3r, bias3l, bias3r);
    k_gemm_db<0, 0, 0, 1, 256><<<GEMM_G * 2, 256, 0, stream>>>(
        h2b, nullptr, wt3l, wt3r, bias3l, t3b, 128, nullptr, bias3r, u3b);
    k_agg_reparam<<<AGG_BLKS, 256, 0, stream>>>(t3b, eids, offs, degc, invd, u3b, eps, z);
}